// Round 1
// baseline (455.500 us; speedup 1.0000x reference)
//
#include <hip/hip_runtime.h>
#include <hip/hip_bf16.h>

#define BB 4
#define SS 2048
#define DD 1024
#define UU 1024
#define NTOK (BB*SS)   // 8192

typedef __attribute__((ext_vector_type(8))) short bf16x8;
typedef __attribute__((ext_vector_type(4))) float f32x4;
typedef __attribute__((ext_vector_type(4))) unsigned short u16x4;
typedef __attribute__((ext_vector_type(8))) unsigned short u16x8;

__device__ inline unsigned short f2bf(float f) {
  unsigned u = __builtin_bit_cast(unsigned, f);
  u += 0x7FFFu + ((u >> 16) & 1u);   // round-to-nearest-even
  return (unsigned short)(u >> 16);
}

// ---------------- cast fp32 -> bf16 (vectorized) ----------------
__global__ __launch_bounds__(256) void cast_f32_bf16(const float* __restrict__ in,
                                                     unsigned short* __restrict__ out,
                                                     long n) {
  long i = ((long)blockIdx.x * blockDim.x + threadIdx.x) * 4;
  long stride = (long)gridDim.x * blockDim.x * 4;
  for (long idx = i; idx < n; idx += stride) {
    float4 v = *(const float4*)(in + idx);
    u16x4 o;
    o[0] = f2bf(v.x); o[1] = f2bf(v.y); o[2] = f2bf(v.z); o[3] = f2bf(v.w);
    *(u16x4*)(out + idx) = o;
  }
}

// ---------------- transpose + cast fp32 [R][C] -> bf16 [C][R] ----------------
__global__ __launch_bounds__(256) void transpose_cast_w(const float* __restrict__ in,
                                                        unsigned short* __restrict__ out,
                                                        int R, int C) {
  __shared__ float tile[32][33];
  int bx = blockIdx.x * 32;  // col base (C)
  int by = blockIdx.y * 32;  // row base (R)
  int tx = threadIdx.x, ty = threadIdx.y;  // (32, 8)
  #pragma unroll
  for (int j = 0; j < 32; j += 8)
    tile[ty + j][tx] = in[(long)(by + ty + j) * C + bx + tx];
  __syncthreads();
  #pragma unroll
  for (int j = 0; j < 32; j += 8)
    out[(long)(bx + ty + j) * R + by + tx] = f2bf(tile[tx][ty + j]);
}

// ---------------- batched bf16 transpose [z][R][C] -> [z][C][R] ----------------
__global__ __launch_bounds__(256) void transpose_bf16_batched(const unsigned short* __restrict__ in,
                                                              unsigned short* __restrict__ out,
                                                              int R, int C) {
  __shared__ unsigned short tile[32][34];
  long z = (long)blockIdx.z * R * C;
  int bx = blockIdx.x * 32;  // col base (C)
  int by = blockIdx.y * 32;  // row base (R)
  int tx = threadIdx.x, ty = threadIdx.y;  // (32, 8)
  #pragma unroll
  for (int j = 0; j < 32; j += 8)
    tile[ty + j][tx] = in[z + (long)(by + ty + j) * C + bx + tx];
  __syncthreads();
  #pragma unroll
  for (int j = 0; j < 32; j += 8)
    out[z + (long)(bx + ty + j) * R + by + tx] = tile[tx][ty + j];
}

// ---------------- generic bf16 GEMM: C[M,N] = alpha * A[M,K] * Bt[N,K]^T + bias ----
// A, Bt bf16; optional fp32 and/or bf16 outputs. Batched via blockIdx.z strides.
// 128x128 tile, BK=64, 256 threads (4 waves, 2x2), mfma_f32_16x16x32_bf16.
__global__ __launch_bounds__(256, 2) void gemm_bt_bf16(
    const unsigned short* __restrict__ A,
    const unsigned short* __restrict__ Bt,
    float* __restrict__ Cf,
    unsigned short* __restrict__ Cb,
    const float* __restrict__ bias,
    const float* __restrict__ alpha_ptr,
    int M, int N, int K,
    long sA, long sB, long sC) {
  __shared__ __align__(16) unsigned short As[128][72];
  __shared__ __align__(16) unsigned short Bs[128][72];

  const int tid = threadIdx.x;
  const int lane = tid & 63;
  const int wid = tid >> 6;
  const int wm = wid >> 1, wn = wid & 1;
  const long zA = (long)blockIdx.z * sA;
  const long zB = (long)blockIdx.z * sB;
  const long zC = (long)blockIdx.z * sC;
  const int m0 = blockIdx.y * 128;
  const int n0 = blockIdx.x * 128;

  f32x4 acc[4][4] = {};

  const int srow = tid >> 3;          // 0..31
  const int scol = (tid & 7) * 8;     // 0..56

  const unsigned short* Ap = A + zA + (long)(m0 + srow) * K + scol;
  const unsigned short* Bp = Bt + zB + (long)(n0 + srow) * K + scol;

  for (int k0 = 0; k0 < K; k0 += 64) {
    #pragma unroll
    for (int p = 0; p < 4; ++p) {
      u16x8 va = *(const u16x8*)(Ap + (long)(p * 32) * K + k0);
      u16x8 vb = *(const u16x8*)(Bp + (long)(p * 32) * K + k0);
      *(u16x8*)&As[srow + p * 32][scol] = va;
      *(u16x8*)&Bs[srow + p * 32][scol] = vb;
    }
    __syncthreads();
    #pragma unroll
    for (int kk = 0; kk < 2; ++kk) {
      bf16x8 af[4], bf_[4];
      #pragma unroll
      for (int m = 0; m < 4; ++m)
        af[m] = *(const bf16x8*)&As[wm * 64 + m * 16 + (lane & 15)][kk * 32 + (lane >> 4) * 8];
      #pragma unroll
      for (int n = 0; n < 4; ++n)
        bf_[n] = *(const bf16x8*)&Bs[wn * 64 + n * 16 + (lane & 15)][kk * 32 + (lane >> 4) * 8];
      #pragma unroll
      for (int m = 0; m < 4; ++m)
        #pragma unroll
        for (int n = 0; n < 4; ++n)
          acc[m][n] = __builtin_amdgcn_mfma_f32_16x16x32_bf16(af[m], bf_[n], acc[m][n], 0, 0, 0);
    }
    __syncthreads();
  }

  const float alpha = alpha_ptr ? *alpha_ptr : 1.0f;
  const int crow0 = m0 + wm * 64 + ((lane >> 4) * 4);
  const int ccol0 = n0 + wn * 64 + (lane & 15);
  #pragma unroll
  for (int m = 0; m < 4; ++m) {
    #pragma unroll
    for (int n = 0; n < 4; ++n) {
      const int cc = ccol0 + n * 16;
      const float bv = bias ? bias[cc] : 0.0f;
      #pragma unroll
      for (int r = 0; r < 4; ++r) {
        const int rr = crow0 + m * 16 + r;
        const float v = acc[m][n][r] * alpha + bv;
        const long idx = zC + (long)rr * N + cc;
        if (Cf) Cf[idx] = v;
        if (Cb) Cb[idx] = f2bf(v);
      }
    }
  }
}

// ---------------- in-place row softmax over 2048 cols; also emit bf16 copy ----
__global__ __launch_bounds__(256) void softmax_rows(float* __restrict__ Wf,
                                                    unsigned short* __restrict__ Pb) {
  const int t = threadIdx.x;
  const int lane = t & 63, wid = t >> 6;
  const long base = (long)blockIdx.x * SS;
  float* p = Wf + base;

  float4 a = *(const float4*)(p + t * 4);
  float4 b = *(const float4*)(p + 1024 + t * 4);

  float m = fmaxf(fmaxf(fmaxf(a.x, a.y), fmaxf(a.z, a.w)),
                  fmaxf(fmaxf(b.x, b.y), fmaxf(b.z, b.w)));
  #pragma unroll
  for (int off = 32; off; off >>= 1) m = fmaxf(m, __shfl_xor(m, off));
  __shared__ float redm[4];
  __shared__ float reds[4];
  if (lane == 0) redm[wid] = m;
  __syncthreads();
  m = fmaxf(fmaxf(redm[0], redm[1]), fmaxf(redm[2], redm[3]));

  float e[8];
  e[0] = __expf(a.x - m); e[1] = __expf(a.y - m); e[2] = __expf(a.z - m); e[3] = __expf(a.w - m);
  e[4] = __expf(b.x - m); e[5] = __expf(b.y - m); e[6] = __expf(b.z - m); e[7] = __expf(b.w - m);
  float s = (e[0] + e[1]) + (e[2] + e[3]) + (e[4] + e[5]) + (e[6] + e[7]);
  #pragma unroll
  for (int off = 32; off; off >>= 1) s += __shfl_xor(s, off);
  if (lane == 0) reds[wid] = s;
  __syncthreads();
  s = (reds[0] + reds[1]) + (reds[2] + reds[3]);
  const float inv = 1.0f / s;

  float4 oa = make_float4(e[0] * inv, e[1] * inv, e[2] * inv, e[3] * inv);
  float4 ob = make_float4(e[4] * inv, e[5] * inv, e[6] * inv, e[7] * inv);
  *(float4*)(p + t * 4) = oa;
  *(float4*)(p + 1024 + t * 4) = ob;

  u16x4 ba, bb2;
  ba[0] = f2bf(oa.x); ba[1] = f2bf(oa.y); ba[2] = f2bf(oa.z); ba[3] = f2bf(oa.w);
  bb2[0] = f2bf(ob.x); bb2[1] = f2bf(ob.y); bb2[2] = f2bf(ob.z); bb2[3] = f2bf(ob.w);
  *(u16x4*)(Pb + base + t * 4) = ba;
  *(u16x4*)(Pb + base + 1024 + t * 4) = bb2;
}

extern "C" void kernel_launch(void* const* d_in, const int* in_sizes, int n_in,
                              void* d_out, int out_size, void* d_ws, size_t ws_size,
                              hipStream_t stream) {
  const float* X     = (const float*)d_in[0];  // [B,S,D]
  const float* Wq    = (const float*)d_in[1];  // [D,U]
  const float* Wk    = (const float*)d_in[2];
  const float* Wv    = (const float*)d_in[3];
  const float* Wo    = (const float*)d_in[4];  // [U,D]
  const float* bo    = (const float*)d_in[5];  // [D]
  const float* scale = (const float*)d_in[6];  // scalar

  float* out = (float*)d_out;                      // [NTOK][D]
  float* wts = out + (long)NTOK * DD;              // [B][S][S] fp32

  // workspace layout (ushorts)
  unsigned short* ws = (unsigned short*)d_ws;
  unsigned short* Xb  = ws;                                  // NTOK*DD  (reused as Cb)
  unsigned short* Qb  = Xb + (long)NTOK * DD;                // NTOK*UU  (reused as Vt)
  unsigned short* Kb  = Qb + (long)NTOK * UU;                // NTOK*UU  (Pb spans Kb..Vb)
  unsigned short* Vb  = Kb + (long)NTOK * UU;                // NTOK*UU
  unsigned short* Wqt = Vb + (long)NTOK * UU;                // UU*DD
  unsigned short* Wkt = Wqt + (long)UU * DD;
  unsigned short* Wvt = Wkt + (long)UU * DD;
  unsigned short* Wot = Wvt + (long)UU * DD;                 // DD*UU
  unsigned short* Cb  = Xb;   // context bf16 (X dead after V GEMM)
  unsigned short* Vt  = Qb;   // V^T per batch (Q dead after scores)
  unsigned short* Pb  = Kb;   // weights bf16 [B][S][S] (K,V dead by then)

  // 1) cast X -> bf16
  cast_f32_bf16<<<2048, 256, 0, stream>>>(X, Xb, (long)NTOK * DD);

  // 2) transpose-cast weights
  transpose_cast_w<<<dim3(UU/32, DD/32), dim3(32, 8), 0, stream>>>(Wq, Wqt, DD, UU);
  transpose_cast_w<<<dim3(UU/32, DD/32), dim3(32, 8), 0, stream>>>(Wk, Wkt, DD, UU);
  transpose_cast_w<<<dim3(UU/32, DD/32), dim3(32, 8), 0, stream>>>(Wv, Wvt, DD, UU);
  transpose_cast_w<<<dim3(DD/32, UU/32), dim3(32, 8), 0, stream>>>(Wo, Wot, UU, DD);

  // 3) Q, K, V projections: [NTOK,DD] x [DD,UU] -> bf16
  dim3 gProj(UU/128, NTOK/128, 1);
  gemm_bt_bf16<<<gProj, 256, 0, stream>>>(Xb, Wqt, nullptr, Qb, nullptr, nullptr,
                                          NTOK, UU, DD, 0, 0, 0);
  gemm_bt_bf16<<<gProj, 256, 0, stream>>>(Xb, Wkt, nullptr, Kb, nullptr, nullptr,
                                          NTOK, UU, DD, 0, 0, 0);
  gemm_bt_bf16<<<gProj, 256, 0, stream>>>(Xb, Wvt, nullptr, Vb, nullptr, nullptr,
                                          NTOK, UU, DD, 0, 0, 0);

  // 4) scores = scale * Q K^T -> fp32 into d_out weights region (batched)
  dim3 gScores(SS/128, SS/128, BB);
  gemm_bt_bf16<<<gScores, 256, 0, stream>>>(Qb, Kb, wts, nullptr, nullptr, scale,
                                            SS, SS, UU,
                                            (long)SS * UU, (long)SS * UU, (long)SS * SS);

  // 5) V^T per batch: [S][U] -> [U][S]  (into Qb region)
  transpose_bf16_batched<<<dim3(UU/32, SS/32, BB), dim3(32, 8), 0, stream>>>(Vb, Vt, SS, UU);

  // 6) softmax in place on wts; bf16 copy into Pb (Kb/Vb region)
  softmax_rows<<<BB * SS, 256, 0, stream>>>(wts, Pb);

  // 7) context = P V  : [S,S] x [S,U] (Bt = V^T [U][S]) -> bf16 Cb
  dim3 gPV(UU/128, SS/128, BB);
  gemm_bt_bf16<<<gPV, 256, 0, stream>>>(Pb, Vt, nullptr, Cb, nullptr, nullptr,
                                        SS, UU, SS,
                                        (long)SS * SS, (long)UU * SS, (long)SS * UU);

  // 8) output = context Wo + bo -> fp32 d_out
  dim3 gOut(DD/128, NTOK/128, 1);
  gemm_bt_bf16<<<gOut, 256, 0, stream>>>(Cb, Wot, out, nullptr, bo, nullptr,
                                         NTOK, DD, UU, 0, 0, 0);
}

// Round 2
// 409.686 us; speedup vs baseline: 1.1118x; 1.1118x over previous
//
#include <hip/hip_runtime.h>
#include <hip/hip_bf16.h>

#define BB 4
#define SS 2048
#define DD 1024
#define UU 1024
#define NTOK (BB*SS)   // 8192

typedef __attribute__((ext_vector_type(8))) short bf16x8;
typedef __attribute__((ext_vector_type(4))) float f32x4;
typedef __attribute__((ext_vector_type(4))) unsigned short u16x4;
typedef __attribute__((ext_vector_type(8))) unsigned short u16x8;

__device__ inline unsigned short f2bf(float f) {
  unsigned u = __builtin_bit_cast(unsigned, f);
  u += 0x7FFFu + ((u >> 16) & 1u);   // round-to-nearest-even
  return (unsigned short)(u >> 16);
}

// async global->LDS, 16B per lane. LDS dest must be wave-uniform (HW writes
// base + lane*16); global src is per-lane.
__device__ inline void gload_lds16(const unsigned short* g, unsigned short* l) {
  __builtin_amdgcn_global_load_lds(
      (const __attribute__((address_space(1))) void*)g,
      (__attribute__((address_space(3))) void*)l, 16, 0, 0);
}

// ---------------- cast fp32 -> bf16 (vectorized) ----------------
__global__ __launch_bounds__(256) void cast_f32_bf16(const float* __restrict__ in,
                                                     unsigned short* __restrict__ out,
                                                     long n) {
  long i = ((long)blockIdx.x * blockDim.x + threadIdx.x) * 4;
  long stride = (long)gridDim.x * blockDim.x * 4;
  for (long idx = i; idx < n; idx += stride) {
    float4 v = *(const float4*)(in + idx);
    u16x4 o;
    o[0] = f2bf(v.x); o[1] = f2bf(v.y); o[2] = f2bf(v.z); o[3] = f2bf(v.w);
    *(u16x4*)(out + idx) = o;
  }
}

// ---------------- transpose + cast fp32 [R][C] -> bf16 [C][R] ----------------
__global__ __launch_bounds__(256) void transpose_cast_w(const float* __restrict__ in,
                                                        unsigned short* __restrict__ out,
                                                        int R, int C) {
  __shared__ float tile[32][33];
  int bx = blockIdx.x * 32;  // col base (C)
  int by = blockIdx.y * 32;  // row base (R)
  int tx = threadIdx.x, ty = threadIdx.y;  // (32, 8)
  #pragma unroll
  for (int j = 0; j < 32; j += 8)
    tile[ty + j][tx] = in[(long)(by + ty + j) * C + bx + tx];
  __syncthreads();
  #pragma unroll
  for (int j = 0; j < 32; j += 8)
    out[(long)(bx + ty + j) * R + by + tx] = f2bf(tile[tx][ty + j]);
}

// ---------------- batched bf16 transpose [z][R][C] -> [z][C][R] ----------------
__global__ __launch_bounds__(256) void transpose_bf16_batched(const unsigned short* __restrict__ in,
                                                              unsigned short* __restrict__ out,
                                                              int R, int C) {
  __shared__ unsigned short tile[32][34];
  long z = (long)blockIdx.z * R * C;
  int bx = blockIdx.x * 32;  // col base (C)
  int by = blockIdx.y * 32;  // row base (R)
  int tx = threadIdx.x, ty = threadIdx.y;  // (32, 8)
  #pragma unroll
  for (int j = 0; j < 32; j += 8)
    tile[ty + j][tx] = in[z + (long)(by + ty + j) * C + bx + tx];
  __syncthreads();
  #pragma unroll
  for (int j = 0; j < 32; j += 8)
    out[z + (long)(bx + ty + j) * R + by + tx] = tile[tx][ty + j];
}

// ---------------- m97-structure bf16 GEMM -----------------------------------
// C[M,N] = alpha * A[M,K] * Bt[N,K]^T (+bias). 128x128 tile, BK=64, 4 waves,
// linear LDS [128][64] staged via global_load_lds width=16 (async DMA),
// 2 barriers per K-step. Batched via blockIdx.z strides.
__global__ __launch_bounds__(256) void gemm_bt_bf16(
    const unsigned short* __restrict__ A,
    const unsigned short* __restrict__ Bt,
    float* __restrict__ Cf,
    unsigned short* __restrict__ Cb,
    const float* __restrict__ bias,
    const float* __restrict__ alpha_ptr,
    int M, int N, int K,
    long sA, long sB, long sC) {
  __shared__ __align__(16) unsigned short As[128 * 64];
  __shared__ __align__(16) unsigned short Bs[128 * 64];

  const int tid = threadIdx.x;
  const int lane = tid & 63;
  const int wid = tid >> 6;
  const int wm = wid >> 1, wn = wid & 1;
  const long zA = (long)blockIdx.z * sA;
  const long zB = (long)blockIdx.z * sB;
  const long zC = (long)blockIdx.z * sC;
  const int m0 = blockIdx.y * 128;
  const int n0 = blockIdx.x * 128;

  f32x4 acc[4][4] = {};

  // staging geometry: wave w stages rows [32w, 32w+32) of As and Bs in 4
  // chunks of 8 rows (1 KiB each). Within a chunk, lane l covers
  // row = 8c + l/8, elems [(l%8)*8, +8).
  const int lrow = lane >> 3;        // 0..7
  const int lcol = (lane & 7) * 8;   // element offset in row
  const unsigned short* Ap = A + zA + (long)(m0 + wid * 32 + lrow) * K + lcol;
  const unsigned short* Bp = Bt + zB + (long)(n0 + wid * 32 + lrow) * K + lcol;
  unsigned short* AsW = &As[(wid * 32) * 64];   // wave-uniform LDS base
  unsigned short* BsW = &Bs[(wid * 32) * 64];

  for (int k0 = 0; k0 < K; k0 += 64) {
    #pragma unroll
    for (int c = 0; c < 4; ++c) {
      gload_lds16(Ap + (long)(c * 8) * K + k0, AsW + (c * 8) * 64);
      gload_lds16(Bp + (long)(c * 8) * K + k0, BsW + (c * 8) * 64);
    }
    __syncthreads();   // compiler emits vmcnt(0) drain here (m97 structure)
    #pragma unroll
    for (int kk = 0; kk < 2; ++kk) {
      bf16x8 af[4], bf_[4];
      #pragma unroll
      for (int m = 0; m < 4; ++m)
        af[m] = *(const bf16x8*)&As[(wm * 64 + m * 16 + (lane & 15)) * 64 + kk * 32 + (lane >> 4) * 8];
      #pragma unroll
      for (int n = 0; n < 4; ++n)
        bf_[n] = *(const bf16x8*)&Bs[(wn * 64 + n * 16 + (lane & 15)) * 64 + kk * 32 + (lane >> 4) * 8];
      #pragma unroll
      for (int m = 0; m < 4; ++m)
        #pragma unroll
        for (int n = 0; n < 4; ++n)
          acc[m][n] = __builtin_amdgcn_mfma_f32_16x16x32_bf16(af[m], bf_[n], acc[m][n], 0, 0, 0);
    }
    __syncthreads();
  }

  const float alpha = alpha_ptr ? *alpha_ptr : 1.0f;
  const int crow0 = m0 + wm * 64 + ((lane >> 4) * 4);
  const int ccol0 = n0 + wn * 64 + (lane & 15);
  #pragma unroll
  for (int m = 0; m < 4; ++m) {
    #pragma unroll
    for (int n = 0; n < 4; ++n) {
      const int cc = ccol0 + n * 16;
      const float bv = bias ? bias[cc] : 0.0f;
      #pragma unroll
      for (int r = 0; r < 4; ++r) {
        const int rr = crow0 + m * 16 + r;
        const float v = acc[m][n][r] * alpha + bv;
        const long idx = zC + (long)rr * N + cc;
        if (Cf) Cf[idx] = v;
        if (Cb) Cb[idx] = f2bf(v);
      }
    }
  }
}

// ---------------- in-place row softmax over 2048 cols; also emit bf16 copy ----
__global__ __launch_bounds__(256) void softmax_rows(float* __restrict__ Wf,
                                                    unsigned short* __restrict__ Pb) {
  const int t = threadIdx.x;
  const int lane = t & 63, wid = t >> 6;
  const long base = (long)blockIdx.x * SS;
  float* p = Wf + base;

  float4 a = *(const float4*)(p + t * 4);
  float4 b = *(const float4*)(p + 1024 + t * 4);

  float m = fmaxf(fmaxf(fmaxf(a.x, a.y), fmaxf(a.z, a.w)),
                  fmaxf(fmaxf(b.x, b.y), fmaxf(b.z, b.w)));
  #pragma unroll
  for (int off = 32; off; off >>= 1) m = fmaxf(m, __shfl_xor(m, off));
  __shared__ float redm[4];
  __shared__ float reds[4];
  if (lane == 0) redm[wid] = m;
  __syncthreads();
  m = fmaxf(fmaxf(redm[0], redm[1]), fmaxf(redm[2], redm[3]));

  float e[8];
  e[0] = __expf(a.x - m); e[1] = __expf(a.y - m); e[2] = __expf(a.z - m); e[3] = __expf(a.w - m);
  e[4] = __expf(b.x - m); e[5] = __expf(b.y - m); e[6] = __expf(b.z - m); e[7] = __expf(b.w - m);
  float s = (e[0] + e[1]) + (e[2] + e[3]) + (e[4] + e[5]) + (e[6] + e[7]);
  #pragma unroll
  for (int off = 32; off; off >>= 1) s += __shfl_xor(s, off);
  if (lane == 0) reds[wid] = s;
  __syncthreads();
  s = (reds[0] + reds[1]) + (reds[2] + reds[3]);
  const float inv = 1.0f / s;

  float4 oa = make_float4(e[0] * inv, e[1] * inv, e[2] * inv, e[3] * inv);
  float4 ob = make_float4(e[4] * inv, e[5] * inv, e[6] * inv, e[7] * inv);
  *(float4*)(p + t * 4) = oa;
  *(float4*)(p + 1024 + t * 4) = ob;

  u16x4 ba, bb2;
  ba[0] = f2bf(oa.x); ba[1] = f2bf(oa.y); ba[2] = f2bf(oa.z); ba[3] = f2bf(oa.w);
  bb2[0] = f2bf(ob.x); bb2[1] = f2bf(ob.y); bb2[2] = f2bf(ob.z); bb2[3] = f2bf(ob.w);
  *(u16x4*)(Pb + base + t * 4) = ba;
  *(u16x4*)(Pb + base + 1024 + t * 4) = bb2;
}

extern "C" void kernel_launch(void* const* d_in, const int* in_sizes, int n_in,
                              void* d_out, int out_size, void* d_ws, size_t ws_size,
                              hipStream_t stream) {
  const float* X     = (const float*)d_in[0];  // [B,S,D]
  const float* Wq    = (const float*)d_in[1];  // [D,U]
  const float* Wk    = (const float*)d_in[2];
  const float* Wv    = (const float*)d_in[3];
  const float* Wo    = (const float*)d_in[4];  // [U,D]
  const float* bo    = (const float*)d_in[5];  // [D]
  const float* scale = (const float*)d_in[6];  // scalar

  float* out = (float*)d_out;                      // [NTOK][D]
  float* wts = out + (long)NTOK * DD;              // [B][S][S] fp32

  // workspace layout (ushorts)
  unsigned short* ws = (unsigned short*)d_ws;
  unsigned short* Xb  = ws;                                  // NTOK*DD  (reused as Cb)
  unsigned short* Qb  = Xb + (long)NTOK * DD;                // NTOK*UU  (reused as Vt)
  unsigned short* Kb  = Qb + (long)NTOK * UU;                // NTOK*UU  (Pb spans Kb..Vb)
  unsigned short* Vb  = Kb + (long)NTOK * UU;                // NTOK*UU
  unsigned short* Wqt = Vb + (long)NTOK * UU;                // UU*DD
  unsigned short* Wkt = Wqt + (long)UU * DD;
  unsigned short* Wvt = Wkt + (long)UU * DD;
  unsigned short* Wot = Wvt + (long)UU * DD;                 // DD*UU
  unsigned short* Cb  = Xb;   // context bf16 (X dead after V GEMM)
  unsigned short* Vt  = Qb;   // V^T per batch (Q dead after scores)
  unsigned short* Pb  = Kb;   // weights bf16 [B][S][S] (K,V dead by then)

  // 1) cast X -> bf16
  cast_f32_bf16<<<2048, 256, 0, stream>>>(X, Xb, (long)NTOK * DD);

  // 2) transpose-cast weights
  transpose_cast_w<<<dim3(UU/32, DD/32), dim3(32, 8), 0, stream>>>(Wq, Wqt, DD, UU);
  transpose_cast_w<<<dim3(UU/32, DD/32), dim3(32, 8), 0, stream>>>(Wk, Wkt, DD, UU);
  transpose_cast_w<<<dim3(UU/32, DD/32), dim3(32, 8), 0, stream>>>(Wv, Wvt, DD, UU);
  transpose_cast_w<<<dim3(DD/32, UU/32), dim3(32, 8), 0, stream>>>(Wo, Wot, UU, DD);

  // 3) Q, K, V projections: [NTOK,DD] x [DD,UU] -> bf16
  dim3 gProj(UU/128, NTOK/128, 1);
  gemm_bt_bf16<<<gProj, 256, 0, stream>>>(Xb, Wqt, nullptr, Qb, nullptr, nullptr,
                                          NTOK, UU, DD, 0, 0, 0);
  gemm_bt_bf16<<<gProj, 256, 0, stream>>>(Xb, Wkt, nullptr, Kb, nullptr, nullptr,
                                          NTOK, UU, DD, 0, 0, 0);
  gemm_bt_bf16<<<gProj, 256, 0, stream>>>(Xb, Wvt, nullptr, Vb, nullptr, nullptr,
                                          NTOK, UU, DD, 0, 0, 0);

  // 4) scores = scale * Q K^T -> fp32 into d_out weights region (batched)
  dim3 gScores(SS/128, SS/128, BB);
  gemm_bt_bf16<<<gScores, 256, 0, stream>>>(Qb, Kb, wts, nullptr, nullptr, scale,
                                            SS, SS, UU,
                                            (long)SS * UU, (long)SS * UU, (long)SS * SS);

  // 5) V^T per batch: [S][U] -> [U][S]  (into Qb region)
  transpose_bf16_batched<<<dim3(UU/32, SS/32, BB), dim3(32, 8), 0, stream>>>(Vb, Vt, SS, UU);

  // 6) softmax in place on wts; bf16 copy into Pb (Kb/Vb region)
  softmax_rows<<<BB * SS, 256, 0, stream>>>(wts, Pb);

  // 7) context = P V  : [S,S] x [S,U] (Bt = V^T [U][S]) -> bf16 Cb
  dim3 gPV(UU/128, SS/128, BB);
  gemm_bt_bf16<<<gPV, 256, 0, stream>>>(Pb, Vt, nullptr, Cb, nullptr, nullptr,
                                        SS, UU, SS,
                                        (long)SS * SS, (long)UU * SS, (long)SS * UU);

  // 8) output = context Wo + bo -> fp32 d_out
  dim3 gOut(DD/128, NTOK/128, 1);
  gemm_bt_bf16<<<gOut, 256, 0, stream>>>(Cb, Wot, out, nullptr, bo, nullptr,
                                         NTOK, DD, UU, 0, 0, 0);
}

// Round 3
// 379.573 us; speedup vs baseline: 1.2000x; 1.0793x over previous
//
#include <hip/hip_runtime.h>
#include <hip/hip_bf16.h>

#define BB 4
#define SS 2048
#define DD 1024
#define UU 1024
#define NTOK (BB*SS)   // 8192

typedef unsigned short ushort_t;
typedef __attribute__((ext_vector_type(8))) short bf16x8;
typedef __attribute__((ext_vector_type(4))) float f32x4;
typedef __attribute__((ext_vector_type(4))) unsigned short u16x4;

__device__ inline unsigned short f2bf(float f) {
  unsigned u = __builtin_bit_cast(unsigned, f);
  u += 0x7FFFu + ((u >> 16) & 1u);   // round-to-nearest-even
  return (unsigned short)(u >> 16);
}

__device__ inline void gload_lds16(const ushort_t* g, ushort_t* l) {
  __builtin_amdgcn_global_load_lds(
      (const __attribute__((address_space(1))) void*)g,
      (__attribute__((address_space(3))) void*)l, 16, 0, 0);
}

#define WAIT_LGKM0 do { asm volatile("s_waitcnt lgkmcnt(0)" ::: "memory"); \
                        __builtin_amdgcn_sched_barrier(0); } while(0)
#define WAIT_VM0   do { asm volatile("s_waitcnt vmcnt(0)" ::: "memory"); \
                        __builtin_amdgcn_sched_barrier(0); } while(0)
#define BAR        do { __builtin_amdgcn_s_barrier(); \
                        __builtin_amdgcn_sched_barrier(0); } while(0)

// ---------------- cast fp32 -> bf16 ----------------
__global__ __launch_bounds__(256) void cast_f32_bf16(const float* __restrict__ in,
                                                     ushort_t* __restrict__ out,
                                                     long n) {
  long i = ((long)blockIdx.x * blockDim.x + threadIdx.x) * 4;
  long stride = (long)gridDim.x * blockDim.x * 4;
  for (long idx = i; idx < n; idx += stride) {
    float4 v = *(const float4*)(in + idx);
    u16x4 o;
    o[0] = f2bf(v.x); o[1] = f2bf(v.y); o[2] = f2bf(v.z); o[3] = f2bf(v.w);
    *(u16x4*)(out + idx) = o;
  }
}

// ---------------- transpose + cast fp32 [R][C] -> bf16 [C][R] ----------------
__global__ __launch_bounds__(256) void transpose_cast_w(const float* __restrict__ in,
                                                        ushort_t* __restrict__ out,
                                                        int R, int C) {
  __shared__ float tile[32][33];
  int bx = blockIdx.x * 32, by = blockIdx.y * 32;
  int tx = threadIdx.x, ty = threadIdx.y;  // (32, 8)
  #pragma unroll
  for (int j = 0; j < 32; j += 8)
    tile[ty + j][tx] = in[(long)(by + ty + j) * C + bx + tx];
  __syncthreads();
  #pragma unroll
  for (int j = 0; j < 32; j += 8)
    out[(long)(bx + ty + j) * R + by + tx] = f2bf(tile[tx][ty + j]);
}

// ---------------- batched bf16 transpose [z][R][C] -> [z][C][R] ----------------
__global__ __launch_bounds__(256) void transpose_bf16_batched(const ushort_t* __restrict__ in,
                                                              ushort_t* __restrict__ out,
                                                              int R, int C) {
  __shared__ ushort_t tile[32][34];
  long z = (long)blockIdx.z * R * C;
  int bx = blockIdx.x * 32, by = blockIdx.y * 32;
  int tx = threadIdx.x, ty = threadIdx.y;
  #pragma unroll
  for (int j = 0; j < 32; j += 8)
    tile[ty + j][tx] = in[z + (long)(by + ty + j) * C + bx + tx];
  __syncthreads();
  #pragma unroll
  for (int j = 0; j < 32; j += 8)
    out[z + (long)(bx + ty + j) * R + by + tx] = tile[tx][ty + j];
}

// ============ 8-phase 256xBN bf16 GEMM (T2 swizzle + T3/T4 pipeline + T5) =====
// C[M,N] = alpha * A[M,K] * Bt[N,K]^T (+bias). BM=256, BK=64, BN in {128,256}.
// 512 threads = 8 waves (2M x 4N); per-wave out 128 x BN/4.
// LDS linear (global_load_lds); swizzle = pre-swizzled global src + XOR'd ds_read.
// Double-buffered K-tiles; stage t+1 during tile t's first 2 phases; one
// vmcnt(0)+barrier per K-tile; raw s_barrier per phase (no compiler drain).
template<int BN>
__global__ __launch_bounds__(512, 2) void gemm8p(
    const ushort_t* __restrict__ A,
    const ushort_t* __restrict__ Bt,
    float* __restrict__ Cf,
    ushort_t* __restrict__ Cb,
    const float* __restrict__ bias,
    const float* __restrict__ alpha_ptr,
    int M, int N, int K,
    long sA, long sB, long sC) {
  static_assert(BN == 128 || BN == 256, "BN");
  constexpr int NREP = BN / 64;         // 4 or 2
  constexpr int BSTEPS = BN / 64;       // B stage steps (64 rows each)
  __shared__ __align__(16) ushort_t As[2][256 * 64];
  __shared__ __align__(16) ushort_t Bs[2][BN * 64];

  const int tid = threadIdx.x;
  const int lane = tid & 63;
  const int wid = tid >> 6;
  const int wm = wid >> 2, wn = wid & 3;   // 2 x 4
  const long zA = (long)blockIdx.z * sA;
  const long zB = (long)blockIdx.z * sB;
  const long zC = (long)blockIdx.z * sC;
  const int m0 = blockIdx.y * 256;
  const int n0 = blockIdx.x * BN;

  f32x4 acc[8][NREP] = {};

  // --- staging map: step j covers rows j*64 + (tid>>3), chunk tid&7 of a
  // [rows][64] bf16 tile (row = 8 chunks of 16B). Global chunk pre-swizzled.
  const int srow = tid >> 3;                         // 0..63
  const int cs = (tid & 7) ^ (srow & 7);             // swizzled source chunk
  const ushort_t* Aps = A + zA + (long)(m0 + srow) * K + cs * 8;
  const ushort_t* Bps = Bt + zB + (long)(n0 + srow) * K + cs * 8;
  const int ldst = (wid * 64) * 8;                   // wave-uniform, +j*512*8

  // ds_read fragment index (swizzled): row R -> R&7 == lane&7
  const int rsel = (lane & 15);
  const int csel = (lane >> 4);
  const int cxor = (lane & 7);

  const int nt = K / 64;

  // prologue: stage tile 0 -> buf 0
  #pragma unroll
  for (int j = 0; j < 4; ++j)
    gload_lds16(Aps + (long)(j * 64) * K, &As[0][j * 4096 + ldst]);
  #pragma unroll
  for (int j = 0; j < BSTEPS; ++j)
    gload_lds16(Bps + (long)(j * 64) * K, &Bs[0][j * 4096 + ldst]);
  WAIT_VM0;
  BAR;

  for (int t = 0; t < nt; ++t) {
    const int cur = t & 1, nxt = cur ^ 1;
    const int k1 = (t + 1) * 64;
    const bool pf = (t + 1 < nt);
    const ushort_t* __restrict__ Ac = &As[cur][0];
    const ushort_t* __restrict__ Bc = &Bs[cur][0];

    bf16x8 bfr[NREP][2], af[4][2];

    // ---------------- phase 0: read all B + A-half0; stage group 0 ----------
    #pragma unroll
    for (int n = 0; n < NREP; ++n)
      #pragma unroll
      for (int kk = 0; kk < 2; ++kk)
        bfr[n][kk] = *(const bf16x8*)&Bc[(wn * (BN/4) + n * 16 + rsel) * 64
                                         + ((kk * 4 + csel) ^ cxor) * 8];
    #pragma unroll
    for (int m = 0; m < 4; ++m)
      #pragma unroll
      for (int kk = 0; kk < 2; ++kk)
        af[m][kk] = *(const bf16x8*)&Ac[(wm * 128 + m * 16 + rsel) * 64
                                        + ((kk * 4 + csel) ^ cxor) * 8];
    if (pf) {
      gload_lds16(Aps + (long)(0 * 64) * K + k1, &As[nxt][0 * 4096 + ldst]);
      gload_lds16(Aps + (long)(1 * 64) * K + k1, &As[nxt][1 * 4096 + ldst]);
      gload_lds16(Bps + (long)(0 * 64) * K + k1, &Bs[nxt][0 * 4096 + ldst]);
      if (BN == 256)
        gload_lds16(Bps + (long)(1 * 64) * K + k1, &Bs[nxt][1 * 4096 + ldst]);
    }
    BAR;
    WAIT_LGKM0;
    __builtin_amdgcn_s_setprio(1);
    #pragma unroll
    for (int m = 0; m < 4; ++m)
      #pragma unroll
      for (int n = 0; n < (NREP == 4 ? 2 : NREP); ++n)
        #pragma unroll
        for (int kk = 0; kk < 2; ++kk)
          acc[m][n] = __builtin_amdgcn_mfma_f32_16x16x32_bf16(af[m][kk], bfr[n][kk], acc[m][n], 0, 0, 0);
    __builtin_amdgcn_s_setprio(0);
    BAR;

    // ---------------- phase 1 ----------------------------------------------
    if (NREP == 4) {
      // stage group 1; MFMA m0-3 x n2-3 (regs resident)
      if (pf) {
        gload_lds16(Aps + (long)(2 * 64) * K + k1, &As[nxt][2 * 4096 + ldst]);
        gload_lds16(Aps + (long)(3 * 64) * K + k1, &As[nxt][3 * 4096 + ldst]);
        gload_lds16(Bps + (long)(2 * 64) * K + k1, &Bs[nxt][2 * 4096 + ldst]);
        gload_lds16(Bps + (long)(3 * 64) * K + k1, &Bs[nxt][3 * 4096 + ldst]);
      }
      BAR;
      __builtin_amdgcn_s_setprio(1);
      #pragma unroll
      for (int m = 0; m < 4; ++m)
        #pragma unroll
        for (int n = 2; n < 4; ++n)
          #pragma unroll
          for (int kk = 0; kk < 2; ++kk)
            acc[m][n] = __builtin_amdgcn_mfma_f32_16x16x32_bf16(af[m][kk], bfr[n][kk], acc[m][n], 0, 0, 0);
      __builtin_amdgcn_s_setprio(0);
      BAR;

      // -------------- phase 2: read A-half1; MFMA m4-7 x n0-1 ---------------
      #pragma unroll
      for (int m = 0; m < 4; ++m)
        #pragma unroll
        for (int kk = 0; kk < 2; ++kk)
          af[m][kk] = *(const bf16x8*)&Ac[(wm * 128 + 64 + m * 16 + rsel) * 64
                                          + ((kk * 4 + csel) ^ cxor) * 8];
      BAR;
      WAIT_LGKM0;
      __builtin_amdgcn_s_setprio(1);
      #pragma unroll
      for (int m = 0; m < 4; ++m)
        #pragma unroll
        for (int n = 0; n < 2; ++n)
          #pragma unroll
          for (int kk = 0; kk < 2; ++kk)
            acc[m + 4][n] = __builtin_amdgcn_mfma_f32_16x16x32_bf16(af[m][kk], bfr[n][kk], acc[m + 4][n], 0, 0, 0);
      __builtin_amdgcn_s_setprio(0);
      BAR;

      // -------------- phase 3: MFMA m4-7 x n2-3 -----------------------------
      __builtin_amdgcn_s_setprio(1);
      #pragma unroll
      for (int m = 0; m < 4; ++m)
        #pragma unroll
        for (int n = 2; n < 4; ++n)
          #pragma unroll
          for (int kk = 0; kk < 2; ++kk)
            acc[m + 4][n] = __builtin_amdgcn_mfma_f32_16x16x32_bf16(af[m][kk], bfr[n][kk], acc[m + 4][n], 0, 0, 0);
      __builtin_amdgcn_s_setprio(0);
    } else {
      // BN=128 phase 1: read A-half1; stage group 1; MFMA m4-7 x n0-1
      #pragma unroll
      for (int m = 0; m < 4; ++m)
        #pragma unroll
        for (int kk = 0; kk < 2; ++kk)
          af[m][kk] = *(const bf16x8*)&Ac[(wm * 128 + 64 + m * 16 + rsel) * 64
                                          + ((kk * 4 + csel) ^ cxor) * 8];
      if (pf) {
        gload_lds16(Aps + (long)(2 * 64) * K + k1, &As[nxt][2 * 4096 + ldst]);
        gload_lds16(Aps + (long)(3 * 64) * K + k1, &As[nxt][3 * 4096 + ldst]);
        gload_lds16(Bps + (long)(1 * 64) * K + k1, &Bs[nxt][1 * 4096 + ldst]);
      }
      BAR;
      WAIT_LGKM0;
      __builtin_amdgcn_s_setprio(1);
      #pragma unroll
      for (int m = 0; m < 4; ++m)
        #pragma unroll
        for (int n = 0; n < NREP; ++n)
          #pragma unroll
          for (int kk = 0; kk < 2; ++kk)
            acc[m + 4][n] = __builtin_amdgcn_mfma_f32_16x16x32_bf16(af[m][kk], bfr[n][kk], acc[m + 4][n], 0, 0, 0);
      __builtin_amdgcn_s_setprio(0);
    }

    // ---------------- K-tile boundary: t+1's loads must have landed ---------
    WAIT_VM0;
    BAR;
  }

  const float alpha = alpha_ptr ? *alpha_ptr : 1.0f;
  const int crow0 = m0 + wm * 128 + csel * 4;
  const int ccol0 = n0 + wn * (BN / 4) + rsel;
  #pragma unroll
  for (int m = 0; m < 8; ++m) {
    #pragma unroll
    for (int n = 0; n < NREP; ++n) {
      const int cc = ccol0 + n * 16;
      const float bv = bias ? bias[cc] : 0.0f;
      #pragma unroll
      for (int r = 0; r < 4; ++r) {
        const int rr = crow0 + m * 16 + r;
        const float v = acc[m][n][r] * alpha + bv;
        const long idx = zC + (long)rr * N + cc;
        if (Cf) Cf[idx] = v;
        if (Cb) Cb[idx] = f2bf(v);
      }
    }
  }
}

// ---------------- in-place row softmax over 2048 cols; also emit bf16 copy ----
__global__ __launch_bounds__(256) void softmax_rows(float* __restrict__ Wf,
                                                    ushort_t* __restrict__ Pb) {
  const int t = threadIdx.x;
  const int lane = t & 63, wid = t >> 6;
  const long base = (long)blockIdx.x * SS;
  float* p = Wf + base;

  float4 a = *(const float4*)(p + t * 4);
  float4 b = *(const float4*)(p + 1024 + t * 4);

  float m = fmaxf(fmaxf(fmaxf(a.x, a.y), fmaxf(a.z, a.w)),
                  fmaxf(fmaxf(b.x, b.y), fmaxf(b.z, b.w)));
  #pragma unroll
  for (int off = 32; off; off >>= 1) m = fmaxf(m, __shfl_xor(m, off));
  __shared__ float redm[4];
  __shared__ float reds[4];
  if (lane == 0) redm[wid] = m;
  __syncthreads();
  m = fmaxf(fmaxf(redm[0], redm[1]), fmaxf(redm[2], redm[3]));

  float e[8];
  e[0] = __expf(a.x - m); e[1] = __expf(a.y - m); e[2] = __expf(a.z - m); e[3] = __expf(a.w - m);
  e[4] = __expf(b.x - m); e[5] = __expf(b.y - m); e[6] = __expf(b.z - m); e[7] = __expf(b.w - m);
  float s = (e[0] + e[1]) + (e[2] + e[3]) + (e[4] + e[5]) + (e[6] + e[7]);
  #pragma unroll
  for (int off = 32; off; off >>= 1) s += __shfl_xor(s, off);
  if (lane == 0) reds[wid] = s;
  __syncthreads();
  s = (reds[0] + reds[1]) + (reds[2] + reds[3]);
  const float inv = 1.0f / s;

  float4 oa = make_float4(e[0] * inv, e[1] * inv, e[2] * inv, e[3] * inv);
  float4 ob = make_float4(e[4] * inv, e[5] * inv, e[6] * inv, e[7] * inv);
  *(float4*)(p + t * 4) = oa;
  *(float4*)(p + 1024 + t * 4) = ob;

  u16x4 ba, bb2;
  ba[0] = f2bf(oa.x); ba[1] = f2bf(oa.y); ba[2] = f2bf(oa.z); ba[3] = f2bf(oa.w);
  bb2[0] = f2bf(ob.x); bb2[1] = f2bf(ob.y); bb2[2] = f2bf(ob.z); bb2[3] = f2bf(ob.w);
  *(u16x4*)(Pb + base + t * 4) = ba;
  *(u16x4*)(Pb + base + 1024 + t * 4) = bb2;
}

extern "C" void kernel_launch(void* const* d_in, const int* in_sizes, int n_in,
                              void* d_out, int out_size, void* d_ws, size_t ws_size,
                              hipStream_t stream) {
  const float* X     = (const float*)d_in[0];
  const float* Wq    = (const float*)d_in[1];
  const float* Wk    = (const float*)d_in[2];
  const float* Wv    = (const float*)d_in[3];
  const float* Wo    = (const float*)d_in[4];
  const float* bo    = (const float*)d_in[5];
  const float* scale = (const float*)d_in[6];

  float* out = (float*)d_out;                      // [NTOK][D]
  float* wts = out + (long)NTOK * DD;              // [B][S][S] fp32

  ushort_t* ws = (ushort_t*)d_ws;
  ushort_t* Xb  = ws;                                  // NTOK*DD  (reused as Cb)
  ushort_t* Qb  = Xb + (long)NTOK * DD;                // NTOK*UU  (reused as Vt)
  ushort_t* Kb  = Qb + (long)NTOK * UU;                // NTOK*UU  (Pb spans Kb..Vb)
  ushort_t* Vb  = Kb + (long)NTOK * UU;                // NTOK*UU
  ushort_t* Wqt = Vb + (long)NTOK * UU;                // UU*DD
  ushort_t* Wkt = Wqt + (long)UU * DD;
  ushort_t* Wvt = Wkt + (long)UU * DD;
  ushort_t* Wot = Wvt + (long)UU * DD;                 // DD*UU
  ushort_t* Cb  = Xb;   // context bf16 (X dead after V GEMM)
  ushort_t* Vt  = Qb;   // V^T per batch (Q dead after scores)
  ushort_t* Pb  = Kb;   // weights bf16 [B][S][S]

  cast_f32_bf16<<<2048, 256, 0, stream>>>(X, Xb, (long)NTOK * DD);

  transpose_cast_w<<<dim3(UU/32, DD/32), dim3(32, 8), 0, stream>>>(Wq, Wqt, DD, UU);
  transpose_cast_w<<<dim3(UU/32, DD/32), dim3(32, 8), 0, stream>>>(Wk, Wkt, DD, UU);
  transpose_cast_w<<<dim3(UU/32, DD/32), dim3(32, 8), 0, stream>>>(Wv, Wvt, DD, UU);
  transpose_cast_w<<<dim3(DD/32, UU/32), dim3(32, 8), 0, stream>>>(Wo, Wot, UU, DD);

  // Q, K, V projections: 256x128 tiles -> grid (8,32) = 256 blocks each
  dim3 gProj(UU/128, NTOK/256, 1);
  gemm8p<128><<<gProj, 512, 0, stream>>>(Xb, Wqt, nullptr, Qb, nullptr, nullptr,
                                         NTOK, UU, DD, 0, 0, 0);
  gemm8p<128><<<gProj, 512, 0, stream>>>(Xb, Wkt, nullptr, Kb, nullptr, nullptr,
                                         NTOK, UU, DD, 0, 0, 0);
  gemm8p<128><<<gProj, 512, 0, stream>>>(Xb, Wvt, nullptr, Vb, nullptr, nullptr,
                                         NTOK, UU, DD, 0, 0, 0);

  // scores = scale * Q K^T : 256x256 tiles -> grid (8,8,4) = 256 blocks
  dim3 gScores(SS/256, SS/256, BB);
  gemm8p<256><<<gScores, 512, 0, stream>>>(Qb, Kb, wts, nullptr, nullptr, scale,
                                           SS, SS, UU,
                                           (long)SS * UU, (long)SS * UU, (long)SS * SS);

  // V^T per batch
  transpose_bf16_batched<<<dim3(UU/32, SS/32, BB), dim3(32, 8), 0, stream>>>(Vb, Vt, SS, UU);

  // softmax in place; bf16 copy to Pb
  softmax_rows<<<BB * SS, 256, 0, stream>>>(wts, Pb);

  // context = P V : 256x128 tiles -> grid (8,8,4) = 256 blocks
  dim3 gPV(UU/128, SS/256, BB);
  gemm8p<128><<<gPV, 512, 0, stream>>>(Pb, Vt, nullptr, Cb, nullptr, nullptr,
                                       SS, UU, SS,
                                       (long)SS * SS, (long)UU * SS, (long)SS * UU);

  // output = context Wo + bo : grid (8,32) = 256 blocks
  dim3 gOut(DD/128, NTOK/256, 1);
  gemm8p<128><<<gOut, 512, 0, stream>>>(Cb, Wot, out, nullptr, bo, nullptr,
                                        NTOK, DD, UU, 0, 0, 0);
}

// Round 4
// 361.093 us; speedup vs baseline: 1.2614x; 1.0512x over previous
//
#include <hip/hip_runtime.h>
#include <hip/hip_bf16.h>

#define BB 4
#define SS 2048
#define DD 1024
#define UU 1024
#define NTOK (BB*SS)   // 8192

typedef unsigned short ushort_t;
typedef __attribute__((ext_vector_type(8))) short bf16x8;
typedef __attribute__((ext_vector_type(4))) float f32x4;
typedef __attribute__((ext_vector_type(4))) unsigned short u16x4;

__device__ inline unsigned short f2bf(float f) {
  unsigned u = __builtin_bit_cast(unsigned, f);
  u += 0x7FFFu + ((u >> 16) & 1u);   // round-to-nearest-even
  return (unsigned short)(u >> 16);
}

__device__ inline void gload_lds16(const ushort_t* g, ushort_t* l) {
  __builtin_amdgcn_global_load_lds(
      (const __attribute__((address_space(1))) void*)g,
      (__attribute__((address_space(3))) void*)l, 16, 0, 0);
}

#define WAIT_LGKM0 do { asm volatile("s_waitcnt lgkmcnt(0)" ::: "memory"); \
                        __builtin_amdgcn_sched_barrier(0); } while(0)
#define WAIT_VM(N) do { asm volatile("s_waitcnt vmcnt(" #N ")" ::: "memory"); \
                        __builtin_amdgcn_sched_barrier(0); } while(0)
#define BAR        do { __builtin_amdgcn_s_barrier(); \
                        __builtin_amdgcn_sched_barrier(0); } while(0)

// ---------------- cast fp32 -> bf16 ----------------
__global__ __launch_bounds__(256) void cast_f32_bf16(const float* __restrict__ in,
                                                     ushort_t* __restrict__ out,
                                                     long n) {
  long i = ((long)blockIdx.x * blockDim.x + threadIdx.x) * 4;
  long stride = (long)gridDim.x * blockDim.x * 4;
  for (long idx = i; idx < n; idx += stride) {
    float4 v = *(const float4*)(in + idx);
    u16x4 o;
    o[0] = f2bf(v.x); o[1] = f2bf(v.y); o[2] = f2bf(v.z); o[3] = f2bf(v.w);
    *(u16x4*)(out + idx) = o;
  }
}

// ------------- fused: 4x transpose+cast fp32 [1024][1024] -> bf16 [C][R] -----
struct TPack { const float* s[4]; ushort_t* d[4]; };
__global__ __launch_bounds__(256) void transpose_cast_w4(TPack p) {
  __shared__ float tile[32][33];
  const float* in = p.s[blockIdx.z];
  ushort_t* out = p.d[blockIdx.z];
  int bx = blockIdx.x * 32, by = blockIdx.y * 32;
  int tx = threadIdx.x, ty = threadIdx.y;  // (32, 8)
  #pragma unroll
  for (int j = 0; j < 32; j += 8)
    tile[ty + j][tx] = in[(long)(by + ty + j) * 1024 + bx + tx];
  __syncthreads();
  #pragma unroll
  for (int j = 0; j < 32; j += 8)
    out[(long)(bx + ty + j) * 1024 + by + tx] = f2bf(tile[tx][ty + j]);
}

// ---------------- batched bf16 transpose [z][R][C] -> [z][C][R] ----------------
__global__ __launch_bounds__(256) void transpose_bf16_batched(const ushort_t* __restrict__ in,
                                                              ushort_t* __restrict__ out,
                                                              int R, int C) {
  __shared__ ushort_t tile[32][34];
  long z = (long)blockIdx.z * R * C;
  int bx = blockIdx.x * 32, by = blockIdx.y * 32;
  int tx = threadIdx.x, ty = threadIdx.y;
  #pragma unroll
  for (int j = 0; j < 32; j += 8)
    tile[ty + j][tx] = in[z + (long)(by + ty + j) * C + bx + tx];
  __syncthreads();
  #pragma unroll
  for (int j = 0; j < 32; j += 8)
    out[z + (long)(bx + ty + j) * R + by + tx] = tile[tx][ty + j];
}

// ============ 8-phase 256xBN bf16 GEMM: T2 swizzle + T3 phases + T4 counted
// vmcnt (never 0 in main loop) + T5 setprio + T1 XCD-aware tile remap.
// C[M,N] = alpha * A[M,K] * Bt[N,K]^T (+bias). BM=256, BK=64.
// 512 threads = 8 waves (2M x 4N). Stage order per tile: B0..B(s-1), A0, A2,
// A1, A3. All of tile t+1 issued in phase 0 of tile t. Waits:
//   mid-tile (before A-half1 read): drain A1,A3(t)  -> vmcnt(g_all)   [oldest 2]
//   boundary: drain B*,A0,A2(t+1)                  -> vmcnt(2)
template<int BN>
__global__ __launch_bounds__(512, 2) void gemm8p(
    const ushort_t* __restrict__ A,
    const ushort_t* __restrict__ Bt,
    float* __restrict__ Cf,
    ushort_t* __restrict__ Cb,
    const float* __restrict__ bias,
    const float* __restrict__ alpha_ptr,
    int M, int N, int K,
    long sA, long sB, long sC) {
  static_assert(BN == 128 || BN == 256, "BN");
  constexpr int NREP = BN / 64;
  constexpr int BSTEPS = BN / 64;
  __shared__ __align__(16) ushort_t As[2][256 * 64];
  __shared__ __align__(16) ushort_t Bs[2][BN * 64];

  const int tid = threadIdx.x;
  const int lane = tid & 63;
  const int wid = tid >> 6;
  const int wm = wid >> 2, wn = wid & 3;   // 2 x 4

  // ---- T1: XCD-aware tile remap (bijective; sharers of an A-panel co-XCD) --
  int bx = blockIdx.x, by = blockIdx.y, bz = blockIdx.z;
  {
    const int gx = gridDim.x, gy = gridDim.y, gz = gridDim.z;
    const int total = gx * gy * gz;
    const int ppx = total >> 3;               // blocks per XCD
    if ((total & 7) == 0 && ppx % gx == 0) {
      const int lin = blockIdx.x + gx * (blockIdx.y + gy * blockIdx.z);
      const int xcd = lin & 7, i = lin >> 3;
      const int p = xcd * (ppx / gx) + i / gx; // panel id (y,z combined)
      bx = i % gx; by = p % gy; bz = p / gy;
    }
  }

  const long zA = (long)bz * sA;
  const long zB = (long)bz * sB;
  const long zC = (long)bz * sC;
  const int m0 = by * 256;
  const int n0 = bx * BN;

  f32x4 acc[8][NREP] = {};

  const int srow = tid >> 3;                         // 0..63
  const int cs = (tid & 7) ^ (srow & 7);             // swizzled source chunk
  const ushort_t* Aps = A + zA + (long)(m0 + srow) * K + cs * 8;
  const ushort_t* Bps = Bt + zB + (long)(n0 + srow) * K + cs * 8;
  const int ldst = wid * 512;                        // wave-uniform LDS base (el)

  const int rsel = (lane & 15);
  const int csel = (lane >> 4);
  const int cxor = (lane & 7);

  const int nt = K / 64;

  // stage whole tile tk into buf b; issue order: B0..B(s-1), A0, A2, A1, A3
  auto STAGE = [&](int tk, int b) {
    const long kof = (long)tk * 64;
    #pragma unroll
    for (int j = 0; j < BSTEPS; ++j)
      gload_lds16(Bps + (long)(j * 64) * K + kof, &Bs[b][j * 4096 + ldst]);
    gload_lds16(Aps + (long)(0 * 64) * K + kof, &As[b][0 * 4096 + ldst]);
    gload_lds16(Aps + (long)(2 * 64) * K + kof, &As[b][2 * 4096 + ldst]);
    gload_lds16(Aps + (long)(1 * 64) * K + kof, &As[b][1 * 4096 + ldst]);
    gload_lds16(Aps + (long)(3 * 64) * K + kof, &As[b][3 * 4096 + ldst]);
  };

  // prologue: tile 0 -> buf 0; wait for B*,A0,A2 (leave A1,A3 in flight)
  STAGE(0, 0);
  WAIT_VM(2);
  BAR;

  for (int t = 0; t < nt; ++t) {
    const int cur = t & 1, nxt = cur ^ 1;
    const bool pf = (t + 1 < nt);
    const ushort_t* __restrict__ Ac = &As[cur][0];
    const ushort_t* __restrict__ Bc = &Bs[cur][0];

    bf16x8 bfr[NREP][2], af[4][2];

    // ---- phase 0: ds_read all B + A-half0; issue ALL of tile t+1 ----------
    #pragma unroll
    for (int n = 0; n < NREP; ++n)
      #pragma unroll
      for (int kk = 0; kk < 2; ++kk)
        bfr[n][kk] = *(const bf16x8*)&Bc[(wn * (BN/4) + n * 16 + rsel) * 64
                                         + ((kk * 4 + csel) ^ cxor) * 8];
    #pragma unroll
    for (int m = 0; m < 4; ++m)
      #pragma unroll
      for (int kk = 0; kk < 2; ++kk)
        af[m][kk] = *(const bf16x8*)&Ac[(wm * 128 + m * 16 + rsel) * 64
                                        + ((kk * 4 + csel) ^ cxor) * 8];
    if (pf) STAGE(t + 1, nxt);
    BAR;
    WAIT_LGKM0;
    __builtin_amdgcn_s_setprio(1);
    #pragma unroll
    for (int m = 0; m < 4; ++m)
      #pragma unroll
      for (int n = 0; n < (NREP == 4 ? 2 : NREP); ++n)
        #pragma unroll
        for (int kk = 0; kk < 2; ++kk)
          acc[m][n] = __builtin_amdgcn_mfma_f32_16x16x32_bf16(af[m][kk], bfr[n][kk], acc[m][n], 0, 0, 0);
    __builtin_amdgcn_s_setprio(0);
    BAR;

    if (NREP == 4) {
      // ---- phase 1: MFMA m0-3 x n2-3 (regs); then mid-tile counted wait ----
      __builtin_amdgcn_s_setprio(1);
      #pragma unroll
      for (int m = 0; m < 4; ++m)
        #pragma unroll
        for (int n = 2; n < 4; ++n)
          #pragma unroll
          for (int kk = 0; kk < 2; ++kk)
            acc[m][n] = __builtin_amdgcn_mfma_f32_16x16x32_bf16(af[m][kk], bfr[n][kk], acc[m][n], 0, 0, 0);
      __builtin_amdgcn_s_setprio(0);
      if (pf) { WAIT_VM(8); } else { WAIT_VM(0); }   // drain A1,A3 of tile t
      BAR;

      // ---- phase 2: ds_read A-half1; MFMA m4-7 x n0-1 ----------------------
      #pragma unroll
      for (int m = 0; m < 4; ++m)
        #pragma unroll
        for (int kk = 0; kk < 2; ++kk)
          af[m][kk] = *(const bf16x8*)&Ac[(wm * 128 + 64 + m * 16 + rsel) * 64
                                          + ((kk * 4 + csel) ^ cxor) * 8];
      BAR;
      WAIT_LGKM0;
      __builtin_amdgcn_s_setprio(1);
      #pragma unroll
      for (int m = 0; m < 4; ++m)
        #pragma unroll
        for (int n = 0; n < 2; ++n)
          #pragma unroll
          for (int kk = 0; kk < 2; ++kk)
            acc[m + 4][n] = __builtin_amdgcn_mfma_f32_16x16x32_bf16(af[m][kk], bfr[n][kk], acc[m + 4][n], 0, 0, 0);
      __builtin_amdgcn_s_setprio(0);
      BAR;

      // ---- phase 3: MFMA m4-7 x n2-3; boundary counted wait ----------------
      __builtin_amdgcn_s_setprio(1);
      #pragma unroll
      for (int m = 0; m < 4; ++m)
        #pragma unroll
        for (int n = 2; n < 4; ++n)
          #pragma unroll
          for (int kk = 0; kk < 2; ++kk)
            acc[m + 4][n] = __builtin_amdgcn_mfma_f32_16x16x32_bf16(af[m][kk], bfr[n][kk], acc[m + 4][n], 0, 0, 0);
      __builtin_amdgcn_s_setprio(0);
      if (pf) { WAIT_VM(2); }                         // drain B*,A0,A2 of t+1
      BAR;
    } else {
      // ---- BN=128 phase 0-end: mid-tile counted wait -----------------------
      if (pf) { WAIT_VM(6); } else { WAIT_VM(0); }   // drain A1,A3 of tile t
      BAR;

      // ---- phase 1: ds_read A-half1; MFMA m4-7 all n; boundary wait --------
      #pragma unroll
      for (int m = 0; m < 4; ++m)
        #pragma unroll
        for (int kk = 0; kk < 2; ++kk)
          af[m][kk] = *(const bf16x8*)&Ac[(wm * 128 + 64 + m * 16 + rsel) * 64
                                          + ((kk * 4 + csel) ^ cxor) * 8];
      BAR;
      WAIT_LGKM0;
      __builtin_amdgcn_s_setprio(1);
      #pragma unroll
      for (int m = 0; m < 4; ++m)
        #pragma unroll
        for (int n = 0; n < NREP; ++n)
          #pragma unroll
          for (int kk = 0; kk < 2; ++kk)
            acc[m + 4][n] = __builtin_amdgcn_mfma_f32_16x16x32_bf16(af[m][kk], bfr[n][kk], acc[m + 4][n], 0, 0, 0);
      __builtin_amdgcn_s_setprio(0);
      if (pf) { WAIT_VM(2); }                         // drain B*,A0,A2 of t+1
      BAR;
    }
  }

  const float alpha = alpha_ptr ? *alpha_ptr : 1.0f;
  const int crow0 = m0 + wm * 128 + csel * 4;
  const int ccol0 = n0 + wn * (BN / 4) + rsel;
  #pragma unroll
  for (int m = 0; m < 8; ++m) {
    #pragma unroll
    for (int n = 0; n < NREP; ++n) {
      const int cc = ccol0 + n * 16;
      const float bv = bias ? bias[cc] : 0.0f;
      #pragma unroll
      for (int r = 0; r < 4; ++r) {
        const int rr = crow0 + m * 16 + r;
        const float v = acc[m][n][r] * alpha + bv;
        const long idx = zC + (long)rr * N + cc;
        if (Cf) Cf[idx] = v;
        if (Cb) Cb[idx] = f2bf(v);
      }
    }
  }
}

// ---------------- in-place row softmax over 2048 cols; also emit bf16 copy ----
__global__ __launch_bounds__(256) void softmax_rows(float* __restrict__ Wf,
                                                    ushort_t* __restrict__ Pb) {
  const int t = threadIdx.x;
  const int lane = t & 63, wid = t >> 6;
  const long base = (long)blockIdx.x * SS;
  float* p = Wf + base;

  float4 a = *(const float4*)(p + t * 4);
  float4 b = *(const float4*)(p + 1024 + t * 4);

  float m = fmaxf(fmaxf(fmaxf(a.x, a.y), fmaxf(a.z, a.w)),
                  fmaxf(fmaxf(b.x, b.y), fmaxf(b.z, b.w)));
  #pragma unroll
  for (int off = 32; off; off >>= 1) m = fmaxf(m, __shfl_xor(m, off));
  __shared__ float redm[4];
  __shared__ float reds[4];
  if (lane == 0) redm[wid] = m;
  __syncthreads();
  m = fmaxf(fmaxf(redm[0], redm[1]), fmaxf(redm[2], redm[3]));

  float e[8];
  e[0] = __expf(a.x - m); e[1] = __expf(a.y - m); e[2] = __expf(a.z - m); e[3] = __expf(a.w - m);
  e[4] = __expf(b.x - m); e[5] = __expf(b.y - m); e[6] = __expf(b.z - m); e[7] = __expf(b.w - m);
  float s = (e[0] + e[1]) + (e[2] + e[3]) + (e[4] + e[5]) + (e[6] + e[7]);
  #pragma unroll
  for (int off = 32; off; off >>= 1) s += __shfl_xor(s, off);
  if (lane == 0) reds[wid] = s;
  __syncthreads();
  s = (reds[0] + reds[1]) + (reds[2] + reds[3]);
  const float inv = 1.0f / s;

  float4 oa = make_float4(e[0] * inv, e[1] * inv, e[2] * inv, e[3] * inv);
  float4 ob = make_float4(e[4] * inv, e[5] * inv, e[6] * inv, e[7] * inv);
  *(float4*)(p + t * 4) = oa;
  *(float4*)(p + 1024 + t * 4) = ob;

  u16x4 ba, bb2;
  ba[0] = f2bf(oa.x); ba[1] = f2bf(oa.y); ba[2] = f2bf(oa.z); ba[3] = f2bf(oa.w);
  bb2[0] = f2bf(ob.x); bb2[1] = f2bf(ob.y); bb2[2] = f2bf(ob.z); bb2[3] = f2bf(ob.w);
  *(u16x4*)(Pb + base + t * 4) = ba;
  *(u16x4*)(Pb + base + 1024 + t * 4) = bb2;
}

extern "C" void kernel_launch(void* const* d_in, const int* in_sizes, int n_in,
                              void* d_out, int out_size, void* d_ws, size_t ws_size,
                              hipStream_t stream) {
  const float* X     = (const float*)d_in[0];
  const float* Wq    = (const float*)d_in[1];
  const float* Wk    = (const float*)d_in[2];
  const float* Wv    = (const float*)d_in[3];
  const float* Wo    = (const float*)d_in[4];
  const float* bo    = (const float*)d_in[5];
  const float* scale = (const float*)d_in[6];

  float* out = (float*)d_out;                      // [NTOK][D]
  float* wts = out + (long)NTOK * DD;              // [B][S][S] fp32

  ushort_t* ws = (ushort_t*)d_ws;
  ushort_t* Xb  = ws;                                  // NTOK*DD  (reused as Cb)
  ushort_t* Qb  = Xb + (long)NTOK * DD;                // NTOK*UU  (reused as Vt)
  ushort_t* Kb  = Qb + (long)NTOK * UU;                // NTOK*UU  (Pb spans Kb..Vb)
  ushort_t* Vb  = Kb + (long)NTOK * UU;                // NTOK*UU
  ushort_t* Wqt = Vb + (long)NTOK * UU;                // UU*DD  (Wqt,Wkt,Wvt contiguous!)
  ushort_t* Wkt = Wqt + (long)UU * DD;
  ushort_t* Wvt = Wkt + (long)UU * DD;
  ushort_t* Wot = Wvt + (long)UU * DD;                 // DD*UU
  ushort_t* Cb  = Xb;   // context bf16 (X dead after V GEMM)
  ushort_t* Vt  = Qb;   // V^T per batch (Q dead after scores)
  ushort_t* Pb  = Kb;   // weights bf16 [B][S][S]

  cast_f32_bf16<<<2048, 256, 0, stream>>>(X, Xb, (long)NTOK * DD);

  TPack tp;
  tp.s[0] = Wq; tp.s[1] = Wk; tp.s[2] = Wv; tp.s[3] = Wo;
  tp.d[0] = Wqt; tp.d[1] = Wkt; tp.d[2] = Wvt; tp.d[3] = Wot;
  transpose_cast_w4<<<dim3(32, 32, 4), dim3(32, 8), 0, stream>>>(tp);

  // fused Q,K,V projections: z selects weight & output (consecutive buffers)
  dim3 gProj(UU/128, NTOK/256, 3);
  gemm8p<128><<<gProj, 512, 0, stream>>>(Xb, Wqt, nullptr, Qb, nullptr, nullptr,
                                         NTOK, UU, DD,
                                         0, (long)UU * DD, (long)NTOK * UU);

  // scores = scale * Q K^T : 256x256 tiles, grid (8,8,4) = 256 blocks
  dim3 gScores(SS/256, SS/256, BB);
  gemm8p<256><<<gScores, 512, 0, stream>>>(Qb, Kb, wts, nullptr, nullptr, scale,
                                           SS, SS, UU,
                                           (long)SS * UU, (long)SS * UU, (long)SS * SS);

  // V^T per batch
  transpose_bf16_batched<<<dim3(UU/32, SS/32, BB), dim3(32, 8), 0, stream>>>(Vb, Vt, SS, UU);

  // softmax in place; bf16 copy to Pb
  softmax_rows<<<BB * SS, 256, 0, stream>>>(wts, Pb);

  // context = P V : grid (8,8,4) = 256 blocks
  dim3 gPV(UU/128, SS/256, BB);
  gemm8p<128><<<gPV, 512, 0, stream>>>(Pb, Vt, nullptr, Cb, nullptr, nullptr,
                                       SS, UU, SS,
                                       (long)SS * SS, (long)UU * SS, (long)SS * UU);

  // output = context Wo + bo : grid (8,32) = 256 blocks
  dim3 gOut(DD/128, NTOK/256, 1);
  gemm8p<128><<<gOut, 512, 0, stream>>>(Cb, Wot, out, nullptr, bo, nullptr,
                                        NTOK, DD, UU, 0, 0, 0);
}

// Round 6
// 356.893 us; speedup vs baseline: 1.2763x; 1.0118x over previous
//
#include <hip/hip_runtime.h>
#include <hip/hip_bf16.h>

#define BB 4
#define SS 2048
#define DD 1024
#define UU 1024
#define NTOK (BB*SS)   // 8192

typedef unsigned short ushort_t;
typedef __attribute__((ext_vector_type(8))) short bf16x8;
typedef __attribute__((ext_vector_type(4))) float f32x4;
typedef __attribute__((ext_vector_type(4))) unsigned short u16x4;

__device__ inline unsigned short f2bf(float f) {
  unsigned u = __builtin_bit_cast(unsigned, f);
  u += 0x7FFFu + ((u >> 16) & 1u);   // round-to-nearest-even
  return (unsigned short)(u >> 16);
}

__device__ inline void gload_lds16(const ushort_t* g, ushort_t* l) {
  __builtin_amdgcn_global_load_lds(
      (const __attribute__((address_space(1))) void*)g,
      (__attribute__((address_space(3))) void*)l, 16, 0, 0);
}

#define WAIT_LGKM0 do { asm volatile("s_waitcnt lgkmcnt(0)" ::: "memory"); \
                        __builtin_amdgcn_sched_barrier(0); } while(0)
#define WAIT_VM(N) do { asm volatile("s_waitcnt vmcnt(" #N ")" ::: "memory"); \
                        __builtin_amdgcn_sched_barrier(0); } while(0)
#define BAR        do { __builtin_amdgcn_s_barrier(); \
                        __builtin_amdgcn_sched_barrier(0); } while(0)

// ---------------- cast fp32 -> bf16 ----------------
__global__ __launch_bounds__(256) void cast_f32_bf16(const float* __restrict__ in,
                                                     ushort_t* __restrict__ out,
                                                     long n) {
  long i = ((long)blockIdx.x * blockDim.x + threadIdx.x) * 4;
  long stride = (long)gridDim.x * blockDim.x * 4;
  for (long idx = i; idx < n; idx += stride) {
    float4 v = *(const float4*)(in + idx);
    u16x4 o;
    o[0] = f2bf(v.x); o[1] = f2bf(v.y); o[2] = f2bf(v.z); o[3] = f2bf(v.w);
    *(u16x4*)(out + idx) = o;
  }
}

// ------------- fused: 4x transpose+cast fp32 [1024][1024] -> bf16 [C][R] -----
struct TPack { const float* s[4]; ushort_t* d[4]; };
__global__ __launch_bounds__(256) void transpose_cast_w4(TPack p) {
  __shared__ float tile[32][33];
  const float* in = p.s[blockIdx.z];
  ushort_t* out = p.d[blockIdx.z];
  int bx = blockIdx.x * 32, by = blockIdx.y * 32;
  int tx = threadIdx.x, ty = threadIdx.y;  // (32, 8)
  #pragma unroll
  for (int j = 0; j < 32; j += 8)
    tile[ty + j][tx] = in[(long)(by + ty + j) * 1024 + bx + tx];
  __syncthreads();
  #pragma unroll
  for (int j = 0; j < 32; j += 8)
    out[(long)(bx + ty + j) * 1024 + by + tx] = f2bf(tile[tx][ty + j]);
}

// ---------------- batched bf16 transpose [z][R][C] -> [z][C][R] ----------------
__global__ __launch_bounds__(256) void transpose_bf16_batched(const ushort_t* __restrict__ in,
                                                              ushort_t* __restrict__ out,
                                                              int R, int C) {
  __shared__ ushort_t tile[32][34];
  long z = (long)blockIdx.z * R * C;
  int bx = blockIdx.x * 32, by = blockIdx.y * 32;
  int tx = threadIdx.x, ty = threadIdx.y;
  #pragma unroll
  for (int j = 0; j < 32; j += 8)
    tile[ty + j][tx] = in[z + (long)(by + ty + j) * C + bx + tx];
  __syncthreads();
  #pragma unroll
  for (int j = 0; j < 32; j += 8)
    out[z + (long)(bx + ty + j) * R + by + tx] = tile[tx][ty + j];
}

// ============ BMx256 bf16 GEMM: T2 swizzle + T3 phases + T4 counted vmcnt +
// T5 setprio + T1 XCD remap. C = alpha * A[M,K] * Bt[N,K]^T (+bias).
// BN=256 fixed; BM in {256,128}. 512 threads = 8 waves (2M x 4N).
// BM=256: wave-tile 128x64, 4 phases/K-tile (q-halves by m).
// BM=128: wave-tile 64x64, 2 phases/K-tile (q-halves by n).
// Stage order per tile:
//   BM=256: B0,B1,B2,B3,A0,A2,A1,A3 -> mid vmcnt(8), boundary vmcnt(2)
//   BM=128: B0,B1,A0,A1,B2,B3       -> P1-entry vmcnt(6), boundary vmcnt(2)
template<int BM>
__global__ __launch_bounds__(512, 2) void gemm8p(
    const ushort_t* __restrict__ A,
    const ushort_t* __restrict__ Bt,
    float* __restrict__ Cf,
    ushort_t* __restrict__ Cb,
    const float* __restrict__ bias,
    const float* __restrict__ alpha_ptr,
    int M, int N, int K,
    long sA, long sB, long sC) {
  static_assert(BM == 128 || BM == 256, "BM");
  constexpr int MR = BM / 32;          // m-frags per wave (8 or 4)
  __shared__ __align__(16) ushort_t As[2][BM * 64];
  __shared__ __align__(16) ushort_t Bs[2][256 * 64];

  const int tid = threadIdx.x;
  const int lane = tid & 63;
  const int wid = tid >> 6;
  const int wm = wid >> 2, wn = wid & 3;   // 2 x 4

  // ---- T1: XCD-aware tile remap (bijective; sharers of an A-panel co-XCD) --
  int bx = blockIdx.x, by = blockIdx.y, bz = blockIdx.z;
  {
    const int gx = gridDim.x, gy = gridDim.y, gz = gridDim.z;
    const int total = gx * gy * gz;
    const int ppx = total >> 3;               // blocks per XCD
    if ((total & 7) == 0 && ppx % gx == 0) {
      const int lin = blockIdx.x + gx * (blockIdx.y + gy * blockIdx.z);
      const int xcd = lin & 7, i = lin >> 3;
      const int p = xcd * (ppx / gx) + i / gx; // panel id (y,z combined)
      bx = i % gx; by = p % gy; bz = p / gy;
    }
  }

  const long zA = (long)bz * sA;
  const long zB = (long)bz * sB;
  const long zC = (long)bz * sC;
  const int m0 = by * BM;
  const int n0 = bx * 256;

  f32x4 acc[MR][4] = {};

  const int srow = tid >> 3;                         // 0..63
  const int cs = (tid & 7) ^ (srow & 7);             // swizzled source chunk
  const ushort_t* Aps = A + zA + (long)(m0 + srow) * K + cs * 8;
  const ushort_t* Bps = Bt + zB + (long)(n0 + srow) * K + cs * 8;
  const int ldst = wid * 512;                        // wave-uniform LDS base (el)

  const int rsel = (lane & 15);
  const int csel = (lane >> 4);
  const int cxor = (lane & 7);

  const int nt = K / 64;

  auto STAGE = [&](int tk, int b) {
    const long kof = (long)tk * 64;
    if (BM == 256) {
      #pragma unroll
      for (int j = 0; j < 4; ++j)
        gload_lds16(Bps + (long)(j * 64) * K + kof, &Bs[b][j * 4096 + ldst]);
      gload_lds16(Aps + (long)(0 * 64) * K + kof, &As[b][0 * 4096 + ldst]);
      gload_lds16(Aps + (long)(2 * 64) * K + kof, &As[b][2 * 4096 + ldst]);
      gload_lds16(Aps + (long)(1 * 64) * K + kof, &As[b][1 * 4096 + ldst]);
      gload_lds16(Aps + (long)(3 * 64) * K + kof, &As[b][3 * 4096 + ldst]);
    } else {
      gload_lds16(Bps + (long)(0 * 64) * K + kof, &Bs[b][0 * 4096 + ldst]);
      gload_lds16(Bps + (long)(1 * 64) * K + kof, &Bs[b][1 * 4096 + ldst]);
      gload_lds16(Aps + (long)(0 * 64) * K + kof, &As[b][0 * 4096 + ldst]);
      gload_lds16(Aps + (long)(1 * 64) * K + kof, &As[b][1 * 4096 + ldst]);
      gload_lds16(Bps + (long)(2 * 64) * K + kof, &Bs[b][2 * 4096 + ldst]);
      gload_lds16(Bps + (long)(3 * 64) * K + kof, &Bs[b][3 * 4096 + ldst]);
    }
  };

  // prologue: tile 0 -> buf 0; leave last 2 loads in flight
  STAGE(0, 0);
  WAIT_VM(2);
  BAR;

  for (int t = 0; t < nt; ++t) {
    const int cur = t & 1, nxt = cur ^ 1;
    const bool pf = (t + 1 < nt);
    const ushort_t* __restrict__ Ac = &As[cur][0];
    const ushort_t* __restrict__ Bc = &Bs[cur][0];

    if constexpr (BM == 256) {
      bf16x8 bfr[4][2], af[4][2];
      // ---- phase 0: ds_read all B + A-half0; issue ALL of tile t+1 --------
      #pragma unroll
      for (int n = 0; n < 4; ++n)
        #pragma unroll
        for (int kk = 0; kk < 2; ++kk)
          bfr[n][kk] = *(const bf16x8*)&Bc[(wn * 64 + n * 16 + rsel) * 64
                                           + ((kk * 4 + csel) ^ cxor) * 8];
      #pragma unroll
      for (int m = 0; m < 4; ++m)
        #pragma unroll
        for (int kk = 0; kk < 2; ++kk)
          af[m][kk] = *(const bf16x8*)&Ac[(wm * 128 + m * 16 + rsel) * 64
                                          + ((kk * 4 + csel) ^ cxor) * 8];
      if (pf) STAGE(t + 1, nxt);
      BAR;
      WAIT_LGKM0;
      __builtin_amdgcn_s_setprio(1);
      #pragma unroll
      for (int m = 0; m < 4; ++m)
        #pragma unroll
        for (int n = 0; n < 2; ++n)
          #pragma unroll
          for (int kk = 0; kk < 2; ++kk)
            acc[m][n] = __builtin_amdgcn_mfma_f32_16x16x32_bf16(af[m][kk], bfr[n][kk], acc[m][n], 0, 0, 0);
      __builtin_amdgcn_s_setprio(0);
      BAR;

      // ---- phase 1: MFMA m0-3 x n2-3; mid-tile counted wait ---------------
      __builtin_amdgcn_s_setprio(1);
      #pragma unroll
      for (int m = 0; m < 4; ++m)
        #pragma unroll
        for (int n = 2; n < 4; ++n)
          #pragma unroll
          for (int kk = 0; kk < 2; ++kk)
            acc[m][n] = __builtin_amdgcn_mfma_f32_16x16x32_bf16(af[m][kk], bfr[n][kk], acc[m][n], 0, 0, 0);
      __builtin_amdgcn_s_setprio(0);
      if (pf) { WAIT_VM(8); } else { WAIT_VM(0); }   // drain A1,A3 of tile t
      BAR;

      // ---- phase 2: ds_read A-half1; MFMA m4-7 x n0-1 ---------------------
      #pragma unroll
      for (int m = 0; m < 4; ++m)
        #pragma unroll
        for (int kk = 0; kk < 2; ++kk)
          af[m][kk] = *(const bf16x8*)&Ac[(wm * 128 + 64 + m * 16 + rsel) * 64
                                          + ((kk * 4 + csel) ^ cxor) * 8];
      BAR;
      WAIT_LGKM0;
      __builtin_amdgcn_s_setprio(1);
      #pragma unroll
      for (int m = 0; m < 4; ++m)
        #pragma unroll
        for (int n = 0; n < 2; ++n)
          #pragma unroll
          for (int kk = 0; kk < 2; ++kk)
            acc[m + 4][n] = __builtin_amdgcn_mfma_f32_16x16x32_bf16(af[m][kk], bfr[n][kk], acc[m + 4][n], 0, 0, 0);
      __builtin_amdgcn_s_setprio(0);
      BAR;

      // ---- phase 3: MFMA m4-7 x n2-3; boundary counted wait ---------------
      __builtin_amdgcn_s_setprio(1);
      #pragma unroll
      for (int m = 0; m < 4; ++m)
        #pragma unroll
        for (int n = 2; n < 4; ++n)
          #pragma unroll
          for (int kk = 0; kk < 2; ++kk)
            acc[m + 4][n] = __builtin_amdgcn_mfma_f32_16x16x32_bf16(af[m][kk], bfr[n][kk], acc[m + 4][n], 0, 0, 0);
      __builtin_amdgcn_s_setprio(0);
      if (pf) { WAIT_VM(2); }                         // drain B*,A0,A2 of t+1
      BAR;
    } else {
      bf16x8 bfr[4][2], af[4][2];
      // ---- phase 0: ds_read A-all + B-lo; issue ALL of tile t+1 -----------
      #pragma unroll
      for (int m = 0; m < 4; ++m)
        #pragma unroll
        for (int kk = 0; kk < 2; ++kk)
          af[m][kk] = *(const bf16x8*)&Ac[(wm * 64 + m * 16 + rsel) * 64
                                          + ((kk * 4 + csel) ^ cxor) * 8];
      #pragma unroll
      for (int n = 0; n < 2; ++n)
        #pragma unroll
        for (int kk = 0; kk < 2; ++kk)
          bfr[n][kk] = *(const bf16x8*)&Bc[(wn * 64 + n * 16 + rsel) * 64
                                           + ((kk * 4 + csel) ^ cxor) * 8];
      if (pf) STAGE(t + 1, nxt);
      BAR;
      WAIT_LGKM0;
      __builtin_amdgcn_s_setprio(1);
      #pragma unroll
      for (int m = 0; m < 4; ++m)
        #pragma unroll
        for (int n = 0; n < 2; ++n)
          #pragma unroll
          for (int kk = 0; kk < 2; ++kk)
            acc[m][n] = __builtin_amdgcn_mfma_f32_16x16x32_bf16(af[m][kk], bfr[n][kk], acc[m][n], 0, 0, 0);
      __builtin_amdgcn_s_setprio(0);
      if (pf) { WAIT_VM(6); } else { WAIT_VM(0); }   // drain B-hi of tile t
      BAR;

      // ---- phase 1: ds_read B-hi; MFMA m0-3 x n2-3; boundary wait ---------
      #pragma unroll
      for (int n = 2; n < 4; ++n)
        #pragma unroll
        for (int kk = 0; kk < 2; ++kk)
          bfr[n][kk] = *(const bf16x8*)&Bc[(wn * 64 + n * 16 + rsel) * 64
                                           + ((kk * 4 + csel) ^ cxor) * 8];
      BAR;
      WAIT_LGKM0;
      __builtin_amdgcn_s_setprio(1);
      #pragma unroll
      for (int m = 0; m < 4; ++m)
        #pragma unroll
        for (int n = 2; n < 4; ++n)
          #pragma unroll
          for (int kk = 0; kk < 2; ++kk)
            acc[m][n] = __builtin_amdgcn_mfma_f32_16x16x32_bf16(af[m][kk], bfr[n][kk], acc[m][n], 0, 0, 0);
      __builtin_amdgcn_s_setprio(0);
      if (pf) { WAIT_VM(2); }                         // drain B-lo,A of t+1
      BAR;
    }
  }

  const float alpha = alpha_ptr ? *alpha_ptr : 1.0f;
  const int crow0 = m0 + wm * (BM / 2) + csel * 4;
  const int ccol0 = n0 + wn * 64 + rsel;
  #pragma unroll
  for (int m = 0; m < MR; ++m) {
    #pragma unroll
    for (int n = 0; n < 4; ++n) {
      const int cc = ccol0 + n * 16;
      const float bv = bias ? bias[cc] : 0.0f;
      #pragma unroll
      for (int r = 0; r < 4; ++r) {
        const int rr = crow0 + m * 16 + r;
        const float v = acc[m][n][r] * alpha + bv;
        const long idx = zC + (long)rr * N + cc;
        if (Cf) Cf[idx] = v;
        if (Cb) Cb[idx] = f2bf(v);
      }
    }
  }
}

// ---------------- in-place row softmax over 2048 cols; also emit bf16 copy ----
__global__ __launch_bounds__(256) void softmax_rows(float* __restrict__ Wf,
                                                    ushort_t* __restrict__ Pb) {
  const int t = threadIdx.x;
  const int lane = t & 63, wid = t >> 6;
  const long base = (long)blockIdx.x * SS;
  float* p = Wf + base;

  float4 a = *(const float4*)(p + t * 4);
  float4 b = *(const float4*)(p + 1024 + t * 4);

  float m = fmaxf(fmaxf(fmaxf(a.x, a.y), fmaxf(a.z, a.w)),
                  fmaxf(fmaxf(b.x, b.y), fmaxf(b.z, b.w)));
  #pragma unroll
  for (int off = 32; off; off >>= 1) m = fmaxf(m, __shfl_xor(m, off));
  __shared__ float redm[4];
  __shared__ float reds[4];
  if (lane == 0) redm[wid] = m;
  __syncthreads();
  m = fmaxf(fmaxf(redm[0], redm[1]), fmaxf(redm[2], redm[3]));

  float e[8];
  e[0] = __expf(a.x - m); e[1] = __expf(a.y - m); e[2] = __expf(a.z - m); e[3] = __expf(a.w - m);
  e[4] = __expf(b.x - m); e[5] = __expf(b.y - m); e[6] = __expf(b.z - m); e[7] = __expf(b.w - m);
  float s = (e[0] + e[1]) + (e[2] + e[3]) + (e[4] + e[5]) + (e[6] + e[7]);
  #pragma unroll
  for (int off = 32; off; off >>= 1) s += __shfl_xor(s, off);
  if (lane == 0) reds[wid] = s;
  __syncthreads();
  s = (reds[0] + reds[1]) + (reds[2] + reds[3]);
  const float inv = 1.0f / s;

  float4 oa = make_float4(e[0] * inv, e[1] * inv, e[2] * inv, e[3] * inv);
  float4 ob = make_float4(e[4] * inv, e[5] * inv, e[6] * inv, e[7] * inv);
  *(float4*)(p + t * 4) = oa;
  *(float4*)(p + 1024 + t * 4) = ob;

  u16x4 ba, bb2;
  ba[0] = f2bf(oa.x); ba[1] = f2bf(oa.y); ba[2] = f2bf(oa.z); ba[3] = f2bf(oa.w);
  bb2[0] = f2bf(ob.x); bb2[1] = f2bf(ob.y); bb2[2] = f2bf(ob.z); bb2[3] = f2bf(ob.w);
  *(u16x4*)(Pb + base + t * 4) = ba;
  *(u16x4*)(Pb + base + 1024 + t * 4) = bb2;
}

extern "C" void kernel_launch(void* const* d_in, const int* in_sizes, int n_in,
                              void* d_out, int out_size, void* d_ws, size_t ws_size,
                              hipStream_t stream) {
  const float* X     = (const float*)d_in[0];
  const float* Wq    = (const float*)d_in[1];
  const float* Wk    = (const float*)d_in[2];
  const float* Wv    = (const float*)d_in[3];
  const float* Wo    = (const float*)d_in[4];
  const float* bo    = (const float*)d_in[5];
  const float* scale = (const float*)d_in[6];

  float* out = (float*)d_out;                      // [NTOK][D]
  float* wts = out + (long)NTOK * DD;              // [B][S][S] fp32

  ushort_t* ws = (ushort_t*)d_ws;
  ushort_t* Xb  = ws;                                  // NTOK*DD  (reused as Cb)
  ushort_t* Qb  = Xb + (long)NTOK * DD;                // NTOK*UU  (reused as Vt)
  ushort_t* Kb  = Qb + (long)NTOK * UU;                // NTOK*UU  (Pb spans Kb..Vb)
  ushort_t* Vb  = Kb + (long)NTOK * UU;                // NTOK*UU
  ushort_t* Wqt = Vb + (long)NTOK * UU;                // UU*DD  (Wqt,Wkt,Wvt contiguous)
  ushort_t* Wkt = Wqt + (long)UU * DD;
  ushort_t* Wvt = Wkt + (long)UU * DD;
  ushort_t* Wot = Wvt + (long)UU * DD;                 // DD*UU
  ushort_t* Cb  = Xb;   // context bf16 (X dead after QKV GEMM)
  ushort_t* Vt  = Qb;   // V^T per batch (Q dead after scores)
  ushort_t* Pb  = Kb;   // weights bf16 [B][S][S]

  cast_f32_bf16<<<2048, 256, 0, stream>>>(X, Xb, (long)NTOK * DD);

  TPack tp;
  tp.s[0] = Wq; tp.s[1] = Wk; tp.s[2] = Wv; tp.s[3] = Wo;
  tp.d[0] = Wqt; tp.d[1] = Wkt; tp.d[2] = Wvt; tp.d[3] = Wot;
  transpose_cast_w4<<<dim3(32, 32, 4), dim3(32, 8), 0, stream>>>(tp);

  // fused Q,K,V projections: 256x256 tiles, z selects weight & output buffer
  dim3 gProj(UU/256, NTOK/256, 3);   // (4,32,3) = 384 blocks
  gemm8p<256><<<gProj, 512, 0, stream>>>(Xb, Wqt, nullptr, Qb, nullptr, nullptr,
                                         NTOK, UU, DD,
                                         0, (long)UU * DD, (long)NTOK * UU);

  // scores = scale * Q K^T : 256x256 tiles, (8,8,4) = 256 blocks
  dim3 gScores(SS/256, SS/256, BB);
  gemm8p<256><<<gScores, 512, 0, stream>>>(Qb, Kb, wts, nullptr, nullptr, scale,
                                           SS, SS, UU,
                                           (long)SS * UU, (long)SS * UU, (long)SS * SS);

  // V^T per batch
  transpose_bf16_batched<<<dim3(UU/32, SS/32, BB), dim3(32, 8), 0, stream>>>(Vb, Vt, SS, UU);

  // softmax in place; bf16 copy to Pb
  softmax_rows<<<BB * SS, 256, 0, stream>>>(wts, Pb);

  // context = P V : 128x256 tiles, (4,16,4) = 256 blocks
  dim3 gPV(UU/256, SS/128, BB);
  gemm8p<128><<<gPV, 512, 0, stream>>>(Pb, Vt, nullptr, Cb, nullptr, nullptr,
                                       SS, UU, SS,
                                       (long)SS * SS, (long)UU * SS, (long)SS * UU);

  // output = context Wo + bo : 128x256 tiles, (4,64) = 256 blocks
  dim3 gOut(DD/256, NTOK/128, 1);
  gemm8p<128><<<gOut, 512, 0, stream>>>(Cb, Wot, out, nullptr, bo, nullptr,
                                        NTOK, DD, UU, 0, 0, 0);
}

// Round 8
// 347.093 us; speedup vs baseline: 1.3123x; 1.0282x over previous
//
#include <hip/hip_runtime.h>
#include <hip/hip_bf16.h>

#define BB 4
#define SS 2048
#define DD 1024
#define UU 1024
#define NTOK (BB*SS)   // 8192

typedef unsigned short ushort_t;
typedef __attribute__((ext_vector_type(8))) short bf16x8;
typedef __attribute__((ext_vector_type(4))) float f32x4;
typedef __attribute__((ext_vector_type(4))) unsigned short u16x4;

__device__ inline unsigned short f2bf(float f) {
  unsigned u = __builtin_bit_cast(unsigned, f);
  u += 0x7FFFu + ((u >> 16) & 1u);   // round-to-nearest-even
  return (unsigned short)(u >> 16);
}

__device__ inline void gload_lds16(const ushort_t* g, ushort_t* l) {
  __builtin_amdgcn_global_load_lds(
      (const __attribute__((address_space(1))) void*)g,
      (__attribute__((address_space(3))) void*)l, 16, 0, 0);
}

#define WAIT_LGKM0 do { asm volatile("s_waitcnt lgkmcnt(0)" ::: "memory"); \
                        __builtin_amdgcn_sched_barrier(0); } while(0)
#define WAIT_LGKM(N) do { asm volatile("s_waitcnt lgkmcnt(" #N ")" ::: "memory"); \
                        __builtin_amdgcn_sched_barrier(0); } while(0)
#define WAIT_VM(N) do { asm volatile("s_waitcnt vmcnt(" #N ")" ::: "memory"); \
                        __builtin_amdgcn_sched_barrier(0); } while(0)
#define BAR        do { __builtin_amdgcn_s_barrier(); \
                        __builtin_amdgcn_sched_barrier(0); } while(0)
#define PRIO1      __builtin_amdgcn_s_setprio(1)
#define PRIO0      __builtin_amdgcn_s_setprio(0)

// ---------------- cast fp32 -> bf16 ----------------
__global__ __launch_bounds__(256) void cast_f32_bf16(const float* __restrict__ in,
                                                     ushort_t* __restrict__ out,
                                                     long n) {
  long i = ((long)blockIdx.x * blockDim.x + threadIdx.x) * 4;
  long stride = (long)gridDim.x * blockDim.x * 4;
  for (long idx = i; idx < n; idx += stride) {
    float4 v = *(const float4*)(in + idx);
    u16x4 o;
    o[0] = f2bf(v.x); o[1] = f2bf(v.y); o[2] = f2bf(v.z); o[3] = f2bf(v.w);
    *(u16x4*)(out + idx) = o;
  }
}

// ------------- fused: 4x transpose+cast fp32 [1024][1024] -> bf16 [C][R] -----
struct TPack { const float* s[4]; ushort_t* d[4]; };
__global__ __launch_bounds__(256) void transpose_cast_w4(TPack p) {
  __shared__ float tile[32][33];
  const float* in = p.s[blockIdx.z];
  ushort_t* out = p.d[blockIdx.z];
  int bx = blockIdx.x * 32, by = blockIdx.y * 32;
  int tx = threadIdx.x, ty = threadIdx.y;  // (32, 8)
  #pragma unroll
  for (int j = 0; j < 32; j += 8)
    tile[ty + j][tx] = in[(long)(by + ty + j) * 1024 + bx + tx];
  __syncthreads();
  #pragma unroll
  for (int j = 0; j < 32; j += 8)
    out[(long)(bx + ty + j) * 1024 + by + tx] = f2bf(tile[tx][ty + j]);
}

// ---------------- batched bf16 transpose [z][R][C] -> [z][C][R] ----------------
__global__ __launch_bounds__(256) void transpose_bf16_batched(const ushort_t* __restrict__ in,
                                                              ushort_t* __restrict__ out,
                                                              int R, int C) {
  __shared__ ushort_t tile[32][34];
  long z = (long)blockIdx.z * R * C;
  int bx = blockIdx.x * 32, by = blockIdx.y * 32;
  int tx = threadIdx.x, ty = threadIdx.y;
  #pragma unroll
  for (int j = 0; j < 32; j += 8)
    tile[ty + j][tx] = in[z + (long)(by + ty + j) * C + bx + tx];
  __syncthreads();
  #pragma unroll
  for (int j = 0; j < 32; j += 8)
    out[z + (long)(bx + ty + j) * R + by + tx] = tile[tx][ty + j];
}

// ---- shared helper macros for the GEMM kernels ------------------------------
// ds_read A frags (4 m-frags x 2 kk) from LDS base Ax, m-row base MB
#define RD_A(Ax, MB) do { \
  _Pragma("unroll") for (int m = 0; m < 4; ++m) \
    _Pragma("unroll") for (int kk = 0; kk < 2; ++kk) \
      af[m][kk] = *(const bf16x8*)&(Ax)[((MB) + m * 16 + rsel) * 64 \
                                        + ((kk * 4 + csel) ^ cxor) * 8]; \
} while(0)
// ds_read B frags (2 n-frags starting at NH*2) from LDS base Bx
#define RD_B(Bx, NH) do { \
  _Pragma("unroll") for (int n = 0; n < 2; ++n) \
    _Pragma("unroll") for (int kk = 0; kk < 2; ++kk) \
      bfr[(NH)*2 + n][kk] = *(const bf16x8*)&(Bx)[(wn * 64 + ((NH)*2 + n) * 16 + rsel) * 64 \
                                                  + ((kk * 4 + csel) ^ cxor) * 8]; \
} while(0)
// 16 MFMA: m-frags MH*4..+3 -> acc rows MH*4+m; n-frags NH*2..+1
#define MM16(MH, NH) do { \
  _Pragma("unroll") for (int m = 0; m < 4; ++m) \
    _Pragma("unroll") for (int n = 0; n < 2; ++n) \
      _Pragma("unroll") for (int kk = 0; kk < 2; ++kk) \
        acc[(MH)*4 + m][(NH)*2 + n] = __builtin_amdgcn_mfma_f32_16x16x32_bf16( \
            af[m][kk], bfr[(NH)*2 + n][kk], acc[(MH)*4 + m][(NH)*2 + n], 0, 0, 0); \
} while(0)

// ============ 256x256 bf16 GEMM, m201-style 8-phase / 2-K-tile schedule ======
// C = alpha * A[M,K] * Bt[N,K]^T (+bias). 512 thr = 8 waves (2M x 4N),
// wave-tile 128x64. LDS 128KB: A,B each 2dbuf x 256x64. Per phase: <=12
// ds_read_b128 + ONE half-tile stage (2 gload_lds) + 2 barriers + 16 MFMA.
// Stage stream (iter reads E=2it at p1-4 from dbuf0, O at p5-8 from dbuf1):
//   p1:A-lo(O) p2:A-hi(O) p3:B-lo(E+2) p4:B-hi(E+2)
//   p5:A-lo(E+2) p6:A-hi(E+2) p7:B-lo(O+2) p8:B-hi(O+2)
// Each stage targets a region past its last ds_read (A(E):p1/p3, B(E):p2).
// Waits: vmcnt(4) at p4 (A(O) landed) and p8 (A,B(E+2) landed).
__global__ __launch_bounds__(512, 2) void gemm256_8p(
    const ushort_t* __restrict__ A,
    const ushort_t* __restrict__ Bt,
    float* __restrict__ Cf,
    ushort_t* __restrict__ Cb,
    const float* __restrict__ bias,
    const float* __restrict__ alpha_ptr,
    int M, int N, int K,
    long sA, long sB, long sC) {
  __shared__ __align__(16) ushort_t As[2][256 * 64];
  __shared__ __align__(16) ushort_t Bs[2][256 * 64];

  const int tid = threadIdx.x;
  const int lane = tid & 63;
  const int wid = tid >> 6;
  const int wm = wid >> 2, wn = wid & 3;

  int bx = blockIdx.x, by = blockIdx.y, bz = blockIdx.z;
  {
    const int gx = gridDim.x, gy = gridDim.y, gz = gridDim.z;
    const int total = gx * gy * gz;
    const int ppx = total >> 3;
    if ((total & 7) == 0 && ppx % gx == 0) {
      const int lin = blockIdx.x + gx * (blockIdx.y + gy * blockIdx.z);
      const int xcd = lin & 7, i = lin >> 3;
      const int p = xcd * (ppx / gx) + i / gx;
      bx = i % gx; by = p % gy; bz = p / gy;
    }
  }

  const long zA = (long)bz * sA;
  const long zB = (long)bz * sB;
  const long zC = (long)bz * sC;
  const int m0 = by * 256;
  const int n0 = bx * 256;

  f32x4 acc[8][4] = {};

  const int srow = tid >> 3;
  const int cs = (tid & 7) ^ (srow & 7);
  const ushort_t* Aps = A + zA + (long)(m0 + srow) * K + cs * 8;
  const ushort_t* Bps = Bt + zB + (long)(n0 + srow) * K + cs * 8;
  const int ldst = wid * 512;

  const int rsel = (lane & 15);
  const int csel = (lane >> 4);
  const int cxor = (lane & 7);

  const int nt = K / 64;          // even
  const int nIter = nt / 2;

  // stage one 64-row block g of tile tk (dbuf = tk&1)
  #define STA256(tk, g) gload_lds16(Aps + (long)((g) * 64) * K + (long)(tk) * 64, \
                                    &As[(tk) & 1][(g) * 4096 + ldst])
  #define STB256(tk, g) gload_lds16(Bps + (long)((g) * 64) * K + (long)(tk) * 64, \
                                    &Bs[(tk) & 1][(g) * 4096 + ldst])

  // prologue: B(0), A(0), B(1); leave B(1) (4 loads) in flight
  STB256(0, 0); STB256(0, 1); STB256(0, 2); STB256(0, 3);
  STA256(0, 0); STA256(0, 1); STA256(0, 2); STA256(0, 3);
  STB256(1, 0); STB256(1, 1); STB256(1, 2); STB256(1, 3);
  WAIT_VM(4);
  BAR;

  for (int it = 0; it < nIter; ++it) {
    const int E = 2 * it, O = E + 1;
    const bool pf = (it + 1 < nIter);
    const ushort_t* __restrict__ Ae = &As[0][0];
    const ushort_t* __restrict__ Be = &Bs[0][0];
    const ushort_t* __restrict__ Ao = &As[1][0];
    const ushort_t* __restrict__ Bo = &Bs[1][0];

    bf16x8 af[4][2], bfr[4][2];

    // ---- p1: A_E m0-3 + B_E n0-1 (12 reads); stage A-lo(O) ----
    RD_A(Ae, wm * 128);
    RD_B(Be, 0);
    STA256(O, 0); STA256(O, 1);
    WAIT_LGKM(8);
    BAR; WAIT_LGKM0;
    PRIO1; MM16(0, 0); PRIO0;
    BAR;

    // ---- p2: B_E n2-3 (4 reads); stage A-hi(O) ----
    RD_B(Be, 1);
    STA256(O, 2); STA256(O, 3);
    BAR; WAIT_LGKM0;
    PRIO1; MM16(0, 1); PRIO0;
    BAR;

    // ---- p3: A_E m4-7 (8 reads); stage B-lo(E+2) ----
    RD_A(Ae, wm * 128 + 64);
    if (pf) { STB256(E + 2, 0); STB256(E + 2, 1); }
    BAR; WAIT_LGKM0;
    PRIO1; MM16(1, 0); PRIO0;
    BAR;

    // ---- p4: no reads; stage B-hi(E+2); wait: A(O) landed ----
    if (pf) { STB256(E + 2, 2); STB256(E + 2, 3); }
    BAR;
    PRIO1; MM16(1, 1); PRIO0;
    if (pf) { WAIT_VM(4); } else { WAIT_VM(0); }
    BAR;

    // ---- p5: A_O m0-3 + B_O n0-1 (12 reads); stage A-lo(E+2) ----
    RD_A(Ao, wm * 128);
    RD_B(Bo, 0);
    if (pf) { STA256(E + 2, 0); STA256(E + 2, 1); }
    WAIT_LGKM(8);
    BAR; WAIT_LGKM0;
    PRIO1; MM16(0, 0); PRIO0;
    BAR;

    // ---- p6: B_O n2-3; stage A-hi(E+2) ----
    RD_B(Bo, 1);
    if (pf) { STA256(E + 2, 2); STA256(E + 2, 3); }
    BAR; WAIT_LGKM0;
    PRIO1; MM16(0, 1); PRIO0;
    BAR;

    // ---- p7: A_O m4-7; stage B-lo(O+2) ----
    RD_A(Ao, wm * 128 + 64);
    if (pf) { STB256(O + 2, 0); STB256(O + 2, 1); }
    BAR; WAIT_LGKM0;
    PRIO1; MM16(1, 0); PRIO0;
    BAR;

    // ---- p8: no reads; stage B-hi(O+2); wait: A,B(E+2) landed ----
    if (pf) { STB256(O + 2, 2); STB256(O + 2, 3); }
    BAR;
    PRIO1; MM16(1, 1); PRIO0;
    if (pf) { WAIT_VM(4); } else { WAIT_VM(0); }
    BAR;
  }

  const float alpha = alpha_ptr ? *alpha_ptr : 1.0f;
  const int crow0 = m0 + wm * 128 + csel * 4;
  const int ccol0 = n0 + wn * 64 + rsel;
  #pragma unroll
  for (int m = 0; m < 8; ++m) {
    #pragma unroll
    for (int n = 0; n < 4; ++n) {
      const int cc = ccol0 + n * 16;
      const float bv = bias ? bias[cc] : 0.0f;
      #pragma unroll
      for (int r = 0; r < 4; ++r) {
        const int rr = crow0 + m * 16 + r;
        const float v = acc[m][n][r] * alpha + bv;
        const long idx = zC + (long)rr * N + cc;
        if (Cf) Cf[idx] = v;
        if (Cb) Cb[idx] = f2bf(v);
      }
    }
  }
  #undef STA256
  #undef STB256
}

// ============ 128x256 bf16 GEMM, 4-phase / 2-K-tile, B triple-buffered =======
// 512 thr = 8 waves (2M x 4N), wave-tile 64x64. LDS 128KB: A 2 x 128x64 (32KB),
// B 3 x 256x64 (96KB). Stage stream (read E at p1-2 dbufA0, O at p3-4 dbufA1;
// B(t) lives in Bs[t%3]):
//   p1: B-lo(E+2)  p2: B-hi(E+2)+A(E+2)  p3: B-lo(O+2)  p4: B-hi(O+2)+A(O+2)
// B(E+2) overwrites B(E-1) (read p3-4 prev iter); B(O+2) overwrites B(E)
// (last read p2 this iter); A(E+2) overwrites A(E) (last read p1).
// Waits: vmcnt(6) at p2 (B,A(O) landed) and p4 (B,A(E+2) landed).
__global__ __launch_bounds__(512, 2) void gemm128_4p(
    const ushort_t* __restrict__ A,
    const ushort_t* __restrict__ Bt,
    float* __restrict__ Cf,
    ushort_t* __restrict__ Cb,
    const float* __restrict__ bias,
    const float* __restrict__ alpha_ptr,
    int M, int N, int K,
    long sA, long sB, long sC) {
  __shared__ __align__(16) ushort_t As[2][128 * 64];
  __shared__ __align__(16) ushort_t Bs[3][256 * 64];

  const int tid = threadIdx.x;
  const int lane = tid & 63;
  const int wid = tid >> 6;
  const int wm = wid >> 2, wn = wid & 3;

  int bx = blockIdx.x, by = blockIdx.y, bz = blockIdx.z;
  {
    const int gx = gridDim.x, gy = gridDim.y, gz = gridDim.z;
    const int total = gx * gy * gz;
    const int ppx = total >> 3;
    if ((total & 7) == 0 && ppx % gx == 0) {
      const int lin = blockIdx.x + gx * (blockIdx.y + gy * blockIdx.z);
      const int xcd = lin & 7, i = lin >> 3;
      const int p = xcd * (ppx / gx) + i / gx;
      bx = i % gx; by = p % gy; bz = p / gy;
    }
  }

  const long zA = (long)bz * sA;
  const long zB = (long)bz * sB;
  const long zC = (long)bz * sC;
  const int m0 = by * 128;
  const int n0 = bx * 256;

  f32x4 acc[4][4] = {};

  const int srow = tid >> 3;
  const int cs = (tid & 7) ^ (srow & 7);
  const ushort_t* Aps = A + zA + (long)(m0 + srow) * K + cs * 8;
  const ushort_t* Bps = Bt + zB + (long)(n0 + srow) * K + cs * 8;
  const int ldst = wid * 512;

  const int rsel = (lane & 15);
  const int csel = (lane >> 4);
  const int cxor = (lane & 7);

  const int nt = K / 64;          // even
  const int nIter = nt / 2;

  #define STA128(tk, g) gload_lds16(Aps + (long)((g) * 64) * K + (long)(tk) * 64, \
                                    &As[(tk) & 1][(g) * 4096 + ldst])
  #define STB128(tk, g) gload_lds16(Bps + (long)((g) * 64) * K + (long)(tk) * 64, \
                                    &Bs[(tk) % 3][(g) * 4096 + ldst])

  // prologue: B(0),A(0),B(1),A(1); leave B(1)+A(1) (6 loads) in flight
  STB128(0, 0); STB128(0, 1); STB128(0, 2); STB128(0, 3);
  STA128(0, 0); STA128(0, 1);
  STB128(1, 0); STB128(1, 1); STB128(1, 2); STB128(1, 3);
  STA128(1, 0); STA128(1, 1);
  WAIT_VM(6);
  BAR;

  for (int it = 0; it < nIter; ++it) {
    const int E = 2 * it, O = E + 1;
    const bool pf = (it + 1 < nIter);
    const ushort_t* __restrict__ Ae = &As[0][0];
    const ushort_t* __restrict__ Ao = &As[1][0];
    const ushort_t* __restrict__ Be = &Bs[E % 3][0];
    const ushort_t* __restrict__ Bo = &Bs[O % 3][0];

    bf16x8 af[4][2], bfr[4][2];

    // ---- p1: A_E all + B_E n0-1 (12 reads); stage B-lo(E+2) ----
    RD_A(Ae, wm * 64);
    RD_B(Be, 0);
    if (pf) { STB128(E + 2, 0); STB128(E + 2, 1); }
    WAIT_LGKM(8);
    BAR; WAIT_LGKM0;
    PRIO1; MM16(0, 0); PRIO0;
    BAR;

    // ---- p2: B_E n2-3 (4 reads); stage B-hi(E+2) + A(E+2); wait O landed ---
    RD_B(Be, 1);
    if (pf) { STB128(E + 2, 2); STB128(E + 2, 3); STA128(E + 2, 0); STA128(E + 2, 1); }
    BAR; WAIT_LGKM0;
    PRIO1; MM16(0, 1); PRIO0;
    if (pf) { WAIT_VM(6); } else { WAIT_VM(0); }
    BAR;

    // ---- p3: A_O all + B_O n0-1 (12 reads); stage B-lo(O+2) ----
    RD_A(Ao, wm * 64);
    RD_B(Bo, 0);
    if (pf) { STB128(O + 2, 0); STB128(O + 2, 1); }
    WAIT_LGKM(8);
    BAR; WAIT_LGKM0;
    PRIO1; MM16(0, 0); PRIO0;
    BAR;

    // ---- p4: B_O n2-3; stage B-hi(O+2) + A(O+2); wait E+2 landed ----
    RD_B(Bo, 1);
    if (pf) { STB128(O + 2, 2); STB128(O + 2, 3); STA128(O + 2, 0); STA128(O + 2, 1); }
    BAR; WAIT_LGKM0;
    PRIO1; MM16(0, 1); PRIO0;
    if (pf) { WAIT_VM(6); } else { WAIT_VM(0); }
    BAR;
  }

  const float alpha = alpha_ptr ? *alpha_ptr : 1.0f;
  const int crow0 = m0 + wm * 64 + csel * 4;
  const int ccol0 = n0 + wn * 64 + rsel;
  #pragma unroll
  for (int m = 0; m < 4; ++m) {
    #pragma unroll
    for (int n = 0; n < 4; ++n) {
      const int cc = ccol0 + n * 16;
      const float bv = bias ? bias[cc] : 0.0f;
      #pragma unroll
      for (int r = 0; r < 4; ++r) {
        const int rr = crow0 + m * 16 + r;
        const float v = acc[m][n][r] * alpha + bv;
        const long idx = zC + (long)rr * N + cc;
        if (Cf) Cf[idx] = v;
        if (Cb) Cb[idx] = f2bf(v);
      }
    }
  }
  #undef STA128
  #undef STB128
}

// ---------------- in-place row softmax over 2048 cols; also emit bf16 copy ----
__global__ __launch_bounds__(256) void softmax_rows(float* __restrict__ Wf,
                                                    ushort_t* __restrict__ Pb) {
  const int t = threadIdx.x;
  const int lane = t & 63, wid = t >> 6;
  const long base = (long)blockIdx.x * SS;
  float* p = Wf + base;

  float4 a = *(const float4*)(p + t * 4);
  float4 b = *(const float4*)(p + 1024 + t * 4);

  float m = fmaxf(fmaxf(fmaxf(a.x, a.y), fmaxf(a.z, a.w)),
                  fmaxf(fmaxf(b.x, b.y), fmaxf(b.z, b.w)));
  #pragma unroll
  for (int off = 32; off; off >>= 1) m = fmaxf(m, __shfl_xor(m, off));
  __shared__ float redm[4];
  __shared__ float reds[4];
  if (lane == 0) redm[wid] = m;
  __syncthreads();
  m = fmaxf(fmaxf(redm[0], redm[1]), fmaxf(redm[2], redm[3]));

  float e[8];
  e[0] = __expf(a.x - m); e[1] = __expf(a.y - m); e[2] = __expf(a.z - m); e[3] = __expf(a.w - m);
  e[4] = __expf(b.x - m); e[5] = __expf(b.y - m); e[6] = __expf(b.z - m); e[7] = __expf(b.w - m);
  float s = (e[0] + e[1]) + (e[2] + e[3]) + (e[4] + e[5]) + (e[6] + e[7]);
  #pragma unroll
  for (int off = 32; off; off >>= 1) s += __shfl_xor(s, off);
  if (lane == 0) reds[wid] = s;
  __syncthreads();
  s = (reds[0] + reds[1]) + (reds[2] + reds[3]);
  const float inv = 1.0f / s;

  float4 oa = make_float4(e[0] * inv, e[1] * inv, e[2] * inv, e[3] * inv);
  float4 ob = make_float4(e[4] * inv, e[5] * inv, e[6] * inv, e[7] * inv);
  *(float4*)(p + t * 4) = oa;
  *(float4*)(p + 1024 + t * 4) = ob;

  u16x4 ba, bb2;
  ba[0] = f2bf(oa.x); ba[1] = f2bf(oa.y); ba[2] = f2bf(oa.z); ba[3] = f2bf(oa.w);
  bb2[0] = f2bf(ob.x); bb2[1] = f2bf(ob.y); bb2[2] = f2bf(ob.z); bb2[3] = f2bf(ob.w);
  *(u16x4*)(Pb + base + t * 4) = ba;
  *(u16x4*)(Pb + base + 1024 + t * 4) = bb2;
}

extern "C" void kernel_launch(void* const* d_in, const int* in_sizes, int n_in,
                              void* d_out, int out_size, void* d_ws, size_t ws_size,
                              hipStream_t stream) {
  const float* X     = (const float*)d_in[0];
  const float* Wq    = (const float*)d_in[1];
  const float* Wk    = (const float*)d_in[2];
  const float* Wv    = (const float*)d_in[3];
  const float* Wo    = (const float*)d_in[4];
  const float* bo    = (const float*)d_in[5];
  const float* scale = (const float*)d_in[6];

  float* out = (float*)d_out;                      // [NTOK][D]
  float* wts = out + (long)NTOK * DD;              // [B][S][S] fp32

  ushort_t* ws = (ushort_t*)d_ws;
  ushort_t* Xb  = ws;                                  // NTOK*DD  (reused as Cb)
  ushort_t* Qb  = Xb + (long)NTOK * DD;                // NTOK*UU  (reused as Vt)
  ushort_t* Kb  = Qb + (long)NTOK * UU;                // NTOK*UU  (Pb spans Kb..Vb)
  ushort_t* Vb  = Kb + (long)NTOK * UU;                // NTOK*UU
  ushort_t* Wqt = Vb + (long)NTOK * UU;                // UU*DD  (Wqt,Wkt,Wvt contiguous)
  ushort_t* Wkt = Wqt + (long)UU * DD;
  ushort_t* Wvt = Wkt + (long)UU * DD;
  ushort_t* Wot = Wvt + (long)UU * DD;                 // DD*UU
  ushort_t* Cb  = Xb;   // context bf16 (X dead after QKV GEMM)
  ushort_t* Vt  = Qb;   // V^T per batch (Q dead after scores)
  ushort_t* Pb  = Kb;   // weights bf16 [B][S][S]

  cast_f32_bf16<<<2048, 256, 0, stream>>>(X, Xb, (long)NTOK * DD);

  TPack tp;
  tp.s[0] = Wq; tp.s[1] = Wk; tp.s[2] = Wv; tp.s[3] = Wo;
  tp.d[0] = Wqt; tp.d[1] = Wkt; tp.d[2] = Wvt; tp.d[3] = Wot;
  transpose_cast_w4<<<dim3(32, 32, 4), dim3(32, 8), 0, stream>>>(tp);

  // fused Q,K,V projections: 256x256 tiles, z selects weight & output buffer
  dim3 gProj(UU/256, NTOK/256, 3);   // 384 blocks
  gemm256_8p<<<gProj, 512, 0, stream>>>(Xb, Wqt, nullptr, Qb, nullptr, nullptr,
                                        NTOK, UU, DD,
                                        0, (long)UU * DD, (long)NTOK * UU);

  // scores = scale * Q K^T : 256x256 tiles, (8,8,4) = 256 blocks
  dim3 gScores(SS/256, SS/256, BB);
  gemm256_8p<<<gScores, 512, 0, stream>>>(Qb, Kb, wts, nullptr, nullptr, scale,
                                          SS, SS, UU,
                                          (long)SS * UU, (long)SS * UU, (long)SS * SS);

  // V^T per batch
  transpose_bf16_batched<<<dim3(UU/32, SS/32, BB), dim3(32, 8), 0, stream>>>(Vb, Vt, SS, UU);

  // softmax in place; bf16 copy to Pb
  softmax_rows<<<BB * SS, 256, 0, stream>>>(wts, Pb);

  // context = P V : 128x256 tiles, (4,16,4) = 256 blocks
  dim3 gPV(UU/256, SS/128, BB);
  gemm128_4p<<<gPV, 512, 0, stream>>>(Pb, Vt, nullptr, Cb, nullptr, nullptr,
                                      SS, UU, SS,
                                      (long)SS * SS, (long)UU * SS, (long)SS * UU);

  // output = context Wo + bo : 128x256 tiles, (4,64) = 256 blocks
  dim3 gOut(DD/256, NTOK/128, 1);
  gemm128_4p<<<gOut, 512, 0, stream>>>(Cb, Wot, out, nullptr, bo, nullptr,
                                       NTOK, DD, UU, 0, 0, 0);
}